// Round 13
// baseline (764.749 us; speedup 1.0000x reference)
//
#include <hip/hip_runtime.h>
#include <hip/hip_bf16.h>
#include <cstdint>

using bf16x8 = __attribute__((ext_vector_type(8))) __bf16;
using floatx4 = __attribute__((ext_vector_type(4))) float;
typedef unsigned short ushort;

#define Nn  512
#define Dd  10
#define Hh  256
#define Ll  128
#define CLS 140
#define ROWS 32768
#define CH  16384

// out buffer (fp32) element offsets
#define OUT_CLASS 1ull
#define OUT_ATOM  4587521ull
#define OUT_ADJ   4751361ull

// byte offsets inside dead out_adj region (67,108,864 B, base ≡ 4 mod 16)
#define T1_OFF 12ull
#define T2_OFF (12ull + 16777216ull)
#define HX_OFF (12ull + 33554432ull)
#define WT_OFF 41943068ull          // region+WT_OFF ≡ 0 mod 16
#define AXS_OFF 45088780ull         // region+AXS_OFF ≡ 0 mod 16
#define ABITS_FB_OFF 47710224ull    // fallback-only abits (unused there; clobber-safe)
#define Z_OFF  50331644ull          // region+Z_OFF ≡ 0 mod 16

static __device__ __forceinline__ ushort bfb(float v) {
    __hip_bfloat16 h = __float2bfloat16(v);
    return *reinterpret_cast<ushort*>(&h);
}
static __device__ __forceinline__ float fbf(ushort u) {
    __hip_bfloat16 h = *reinterpret_cast<__hip_bfloat16*>(&u);
    return __bfloat162float(h);
}
static __device__ __forceinline__ unsigned pk2(float a, float b) {
    return (unsigned)bfb(a) | ((unsigned)bfb(b) << 16);
}

// ================= prep: weight convert/transpose to bf16 =================
// mode 0: transpose convert dst[n*Kp+k]
// mode 1: plain convert
// mode >= 64: strided write into [Cp][64] hi|lo layout: dst[n*64 + (mode-64) + k];
//             (mode-64) >= 32 -> store lo part: bf16(v - fbf(bf16(v)))
struct PDesc { const float* src; ushort* dst; int srcR, srcC, Cp, Kp, tile0, mode; };
struct PTable { PDesc d[18]; };

__global__ __launch_bounds__(256) void prep_kernel(PTable tab) {
    __shared__ float tile[32][33];
    int bt = blockIdx.x, tid = threadIdx.x;
    int di = 0;
    #pragma unroll
    for (int i = 1; i < 18; ++i) if (bt >= tab.d[i].tile0) di = i;
    PDesc d = tab.d[di];
    int lt = bt - d.tile0;
    if (d.mode == 1) {  // plain convert
        long base = (long)lt * 8192;
        const float* s = d.src;
        ushort* o = d.dst;
        for (int i = tid; i < 2048; i += 256) {
            long idx = base + (long)i * 4;
            float4 v = *(const float4*)&s[idx];
            unsigned u0 = pk2(v.x, v.y), u1 = pk2(v.z, v.w);
            *(uint2*)&o[idx] = (uint2){u0, u1};
        }
        return;
    }
    int tilesK = (d.Kp + 31) >> 5;
    int k0 = (lt % tilesK) << 5, n0 = (lt / tilesK) << 5;
    int tx = tid & 31, ty = tid >> 5;
    for (int ky = ty; ky < 32; ky += 8) {
        int k = k0 + ky, n = n0 + tx;
        float v = (k < d.srcR && n < d.srcC) ? d.src[(size_t)k * d.srcC + n] : 0.f;
        tile[ky][tx] = v;
    }
    __syncthreads();
    for (int ny = ty; ny < 32; ny += 8) {
        int n = n0 + ny, k = k0 + tx;
        if (n < d.Cp && k < d.Kp) {
            float v = tile[tx][ny];
            if (d.mode >= 64) {
                int koff = d.mode - 64;
                ushort u;
                if (koff >= 32) u = bfb(v - fbf(bfb(v)));   // lo residual
                else u = bfb(v);                            // hi
                d.dst[(size_t)n * 64 + koff + k] = u;
            } else {
                d.dst[(size_t)n * d.Kp + k] = bfb(v);
            }
        }
    }
}

// ================= encoder stage 1: adj aggregation + adj>0 bitpack =================
// float4 adj loads (16B/lane). Lane l16 handles columns 4*l16+64*it+{0..3}.
// abits layout unchanged: bit for column c at abits[row*32 + c/16], bit c%16.
__global__ __launch_bounds__(256, 8) void agg_kernel(
    const float* __restrict__ adj, const float* __restrict__ x,
    float* __restrict__ axs_g, ushort* __restrict__ abits)
{
    __shared__ float4 xs4[1536];            // 512 rows x 12 floats (padded)
    float* xs = (float*)xs4;
    int tid = threadIdx.x;
    int rowbase = blockIdx.x * 16;
    int b = rowbase >> 9, rowloc = rowbase & 511;
    const float* xb = x + (size_t)b * 5120;
    for (int e = tid; e < 6144; e += 256) {
        int j = e / 12, d = e - j * 12;
        xs[e] = (d < 10) ? xb[j * 10 + d] : 0.f;
    }
    __syncthreads();
    int g = tid >> 4, l16 = tid & 15;
    int row = rowbase + g;
    const float4* arow4 = (const float4*)(adj + (size_t)row * Nn);
    float accv[10] = {};
    float deg = 0.f;
    #define ACCUM(a_, j_) do { float a = (a_); if (a != 0.f) {               \
        const float4 v0 = xs4[(j_) * 3 + 0];                                 \
        const float4 v1 = xs4[(j_) * 3 + 1];                                 \
        const float4 v2 = xs4[(j_) * 3 + 2];                                 \
        deg += a;                                                            \
        accv[0] += a * v0.x; accv[1] += a * v0.y;                            \
        accv[2] += a * v0.z; accv[3] += a * v0.w;                            \
        accv[4] += a * v1.x; accv[5] += a * v1.y;                            \
        accv[6] += a * v1.z; accv[7] += a * v1.w;                            \
        accv[8] += a * v2.x; accv[9] += a * v2.y; } } while (0)
    #pragma unroll
    for (int it = 0; it < 8; ++it) {
        float4 av = arow4[l16 + (it << 4)];
        int nib = ((av.x > 0.f) ? 1 : 0) | ((av.y > 0.f) ? 2 : 0) |
                  ((av.z > 0.f) ? 4 : 0) | ((av.w > 0.f) ? 8 : 0);
        int n2 = nib | (__shfl_xor(nib, 1) << 4);
        int n4 = n2 | (__shfl_xor(n2, 2) << 8);
        if ((l16 & 3) == 0) abits[(size_t)row * 32 + it * 4 + (l16 >> 2)] = (ushort)n4;
        int jb = 4 * l16 + (it << 6);
        ACCUM(av.x, jb + 0);
        ACCUM(av.y, jb + 1);
        ACCUM(av.z, jb + 2);
        ACCUM(av.w, jb + 3);
    }
    #undef ACCUM
    #pragma unroll
    for (int o = 8; o > 0; o >>= 1) {
        deg += __shfl_xor(deg, o);
        #pragma unroll
        for (int d = 0; d < 10; ++d) accv[d] += __shfl_xor(accv[d], o);
    }
    float* orow = axs_g + (size_t)row * 20;
    if (l16 == 0) {
        float dg = fmaxf(deg, 1.f);
        #pragma unroll
        for (int d = 0; d < 10; ++d) orow[d] = accv[d] / dg;
    }
    if (l16 < 10) orow[10 + l16] = xs[(rowloc + g) * 12 + l16];
}

// ================= encoder stage 2: all-MFMA h -> mu/lv -> z + KL =================
// (r10 structure + ILP fix) Weight loads hoisted into registers before each MFMA
// chain -> all L2 round-trips overlap instead of serializing (VGPR 44 -> ~110).
__global__ __launch_bounds__(256, 4) void enc2_kernel(
    const float* __restrict__ axs_g,
    const ushort* __restrict__ Wenc,       // [256][64] bf16: k<10 rel-hi, 10..19 root-hi, 32..41 rel-lo, 42..51 root-lo, rest 0
    const float* __restrict__ brel, const int* __restrict__ nmask,
    const ushort* __restrict__ Wtmu, const float* __restrict__ bmu,
    const ushort* __restrict__ Wtlv, const float* __restrict__ blv,
    const float* __restrict__ eps, float* __restrict__ Z,
    double* __restrict__ acc_kl)
{
    __shared__ float sml[4096];             // [2][16][128] mu/lv (16 KB)
    __shared__ uint4 axsbRaw[160];          // 16 x 80 ushorts (hi at d<20, lo at 40..59)
    __shared__ uint4 hsbRaw[528];           // 16 x 264 ushorts
    __shared__ int smask[16];
    __shared__ float skred[4];
    ushort* axsb = (ushort*)axsbRaw;
    ushort* hsb = (ushort*)hsbRaw;
    int tid = threadIdx.x;
    int rowbase = blockIdx.x * 16;
    size_t abase = (size_t)rowbase * 20;

    // phase A: stage axs as split-bf16 A fragments
    for (int e = tid; e < 1280; e += 256) {
        int r = e / 80, d = e - r * 80;
        ushort u = 0;
        if (d < 20) {
            u = bfb(axs_g[abase + r * 20 + d]);
        } else if (d >= 40 && d < 60) {
            float v = axs_g[abase + r * 20 + d - 40];
            u = bfb(v - fbf(bfb(v)));
        }
        axsb[e] = u;
    }
    if (tid < 16) smask[tid] = nmask[rowbase + tid];
    __syncthreads();

    int lane = tid & 63, wid = tid >> 6;
    int l15 = lane & 15, quad = lane >> 4;

    // phase 2: h via MFMA (M=16, N=256, K=32), split hi/lo for fp32 accuracy.
    // All 8 Wenc vectors preloaded -> loads overlap.
    {
        bf16x8 ah = __builtin_bit_cast(bf16x8, *(const uint4*)(axsb + l15 * 80 + quad * 8));
        bf16x8 al = __builtin_bit_cast(bf16x8, *(const uint4*)(axsb + l15 * 80 + 40 + quad * 8));
        uint4 wh[4], wl2[4];
        #pragma unroll
        for (int i = 0; i < 4; ++i) {
            int col = (wid * 4 + i) * 16 + l15;
            wh[i]  = *(const uint4*)(Wenc + (size_t)col * 64 + quad * 8);
            wl2[i] = *(const uint4*)(Wenc + (size_t)col * 64 + 32 + quad * 8);
        }
        #pragma unroll
        for (int i = 0; i < 4; ++i) {
            int col = (wid * 4 + i) * 16 + l15;
            bf16x8 bh = __builtin_bit_cast(bf16x8, wh[i]);
            bf16x8 blo = __builtin_bit_cast(bf16x8, wl2[i]);
            floatx4 a = (floatx4){0.f, 0.f, 0.f, 0.f};
            a = __builtin_amdgcn_mfma_f32_16x16x32_bf16(al, bh, a, 0, 0, 0);
            a = __builtin_amdgcn_mfma_f32_16x16x32_bf16(ah, blo, a, 0, 0, 0);
            a = __builtin_amdgcn_mfma_f32_16x16x32_bf16(ah, bh, a, 0, 0, 0);
            float bb = brel[col];
            #pragma unroll
            for (int r4 = 0; r4 < 4; ++r4) {
                int row = quad * 4 + r4;
                float v = a[r4] + bb;
                v = (smask[row] != 0) ? fmaxf(v, 0.f) : 0.f;
                hsb[row * 264 + col] = bfb(v);
            }
        }
    }
    __syncthreads();

    // phase 3: mu/lv MFMA -> sml. Per col-tile, all 16 weight vectors preloaded
    // (64 VGPR) -> single L2 latency instead of 8 serialized round-trips.
    #pragma unroll
    for (int i = 0; i < 2; ++i) {
        int ct = wid * 2 + i;
        int col = ct * 16 + l15;
        uint4 wmv[8], wlv[8];
        #pragma unroll
        for (int k0 = 0; k0 < 8; ++k0) {
            wmv[k0] = *(const uint4*)(Wtmu + (size_t)col * 256 + k0 * 32 + quad * 8);
            wlv[k0] = *(const uint4*)(Wtlv + (size_t)col * 256 + k0 * 32 + quad * 8);
        }
        floatx4 amu = (floatx4){0.f, 0.f, 0.f, 0.f};
        floatx4 alv = (floatx4){0.f, 0.f, 0.f, 0.f};
        #pragma unroll
        for (int k0 = 0; k0 < 8; ++k0) {
            bf16x8 af = __builtin_bit_cast(bf16x8, *(const uint4*)(hsb + l15 * 264 + k0 * 32 + quad * 8));
            amu = __builtin_amdgcn_mfma_f32_16x16x32_bf16(af, __builtin_bit_cast(bf16x8, wmv[k0]), amu, 0, 0, 0);
            alv = __builtin_amdgcn_mfma_f32_16x16x32_bf16(af, __builtin_bit_cast(bf16x8, wlv[k0]), alv, 0, 0, 0);
        }
        float bmv = bmu[col], blv_ = blv[col];
        #pragma unroll
        for (int r4 = 0; r4 < 4; ++r4) {
            int row = quad * 4 + r4;
            sml[row * 128 + col] = amu[r4] + bmv;
            sml[2048 + row * 128 + col] = alv[r4] + blv_;
        }
    }
    __syncthreads();

    // phase 4: z + KL, fully coalesced float4 (thread t -> f4 idx t and t+256)
    {
        float kt = 0.f;
        const float4* ep4 = (const float4*)(eps + (size_t)rowbase * Ll);
        float4* z4 = (float4*)(Z + (size_t)rowbase * Ll);
        const float4* mu4 = (const float4*)sml;
        const float4* lv4 = (const float4*)(sml + 2048);
        #pragma unroll
        for (int i = 0; i < 2; ++i) {
            int e4 = tid + i * 256;
            float4 ee = ep4[e4];
            float4 mu = mu4[e4];
            float4 lv = lv4[e4];
            float4 zz;
            zz.x = mu.x + ee.x * expf(0.5f * lv.x);
            zz.y = mu.y + ee.y * expf(0.5f * lv.y);
            zz.z = mu.z + ee.z * expf(0.5f * lv.z);
            zz.w = mu.w + ee.w * expf(0.5f * lv.w);
            z4[e4] = zz;
            kt += 1.f + lv.x - mu.x * mu.x - expf(lv.x);
            kt += 1.f + lv.y - mu.y * mu.y - expf(lv.y);
            kt += 1.f + lv.z - mu.z * mu.z - expf(lv.z);
            kt += 1.f + lv.w - mu.w * mu.w - expf(lv.w);
        }
        #pragma unroll
        for (int o = 32; o > 0; o >>= 1) kt += __shfl_xor(kt, o);
        if (lane == 0) skred[wid] = kt;
    }
    __syncthreads();
    if (tid == 0) atomicAdd(acc_kl, (double)(skred[0] + skred[1] + skred[2] + skred[3]));
}

// ================= unified MFMA GEMM: C = relu?(A @ Bt^T + bias) =================
// A row-major [M][K] fp32 or bf16; Bt bf16 [N][K]; C bf16 or fp32, row stride ldc.
// XCD-aware block swizzle (bijective, requires gridDim.x*gridDim.y % 8 == 0).
__global__ __launch_bounds__(256) void mgemm_kernel(const void* __restrict__ A, int a_bf16,
                                                    const ushort* __restrict__ Bt,
                                                    const float* __restrict__ bias,
                                                    void* __restrict__ Cp, int c_fp32,
                                                    int N, int K, int ldc, int relu) {
    __shared__ uint4 AsRaw[640];
    __shared__ uint4 BsRaw[640];
    ushort* As = (ushort*)AsRaw;
    ushort* Bs = (ushort*)BsRaw;
    int tid = threadIdx.x;
    int nwg = gridDim.x * gridDim.y;
    int bid = blockIdx.y * gridDim.x + blockIdx.x;
    int swz = (bid & 7) * (nwg >> 3) + (bid >> 3);
    int row0 = (swz / gridDim.x) << 7, col0 = (swz % gridDim.x) << 7;
    int lane = tid & 63, wid = tid >> 6;
    int wm = (wid >> 1) * 64, wn = (wid & 1) * 64;
    int l15 = lane & 15, quad = lane >> 4;
    floatx4 acc[4][4];
    #pragma unroll
    for (int i = 0; i < 4; ++i)
        #pragma unroll
        for (int j = 0; j < 4; ++j) acc[i][j] = (floatx4){0.f, 0.f, 0.f, 0.f};
    int am = tid & 127, aseg = tid >> 7;
    for (int k0 = 0; k0 < K; k0 += 32) {
        {
            uint4* dst = (uint4*)(As + am * 40 + aseg * 16);
            if (a_bf16) {
                const uint4* ap = (const uint4*)((const ushort*)A + (size_t)(row0 + am) * K + k0 + aseg * 16);
                dst[0] = ap[0]; dst[1] = ap[1];
            } else {
                const float4* ap = (const float4*)((const float*)A + (size_t)(row0 + am) * K + k0 + aseg * 16);
                float4 f0 = ap[0], f1 = ap[1], f2 = ap[2], f3 = ap[3];
                dst[0] = (uint4){pk2(f0.x, f0.y), pk2(f0.z, f0.w), pk2(f1.x, f1.y), pk2(f1.z, f1.w)};
                dst[1] = (uint4){pk2(f2.x, f2.y), pk2(f2.z, f2.w), pk2(f3.x, f3.y), pk2(f3.z, f3.w)};
            }
        }
        {
            const uint4* bp = (const uint4*)(Bt + (size_t)(col0 + am) * K + k0 + aseg * 16);
            uint4* dst = (uint4*)(Bs + am * 40 + aseg * 16);
            dst[0] = bp[0]; dst[1] = bp[1];
        }
        __syncthreads();
        bf16x8 af[4], bfv[4];
        #pragma unroll
        for (int mt = 0; mt < 4; ++mt)
            af[mt] = __builtin_bit_cast(bf16x8, *(const uint4*)(As + (wm + mt * 16 + l15) * 40 + quad * 8));
        #pragma unroll
        for (int nt = 0; nt < 4; ++nt)
            bfv[nt] = __builtin_bit_cast(bf16x8, *(const uint4*)(Bs + (wn + nt * 16 + l15) * 40 + quad * 8));
        #pragma unroll
        for (int mt = 0; mt < 4; ++mt)
            #pragma unroll
            for (int nt = 0; nt < 4; ++nt)
                acc[mt][nt] = __builtin_amdgcn_mfma_f32_16x16x32_bf16(af[mt], bfv[nt], acc[mt][nt], 0, 0, 0);
        __syncthreads();
    }
    // epilogue: mt,r outer / nt inner (adjacent store chunks per row -> better combining)
    float bvv[4];
    int ncols[4];
    #pragma unroll
    for (int nt = 0; nt < 4; ++nt) {
        ncols[nt] = col0 + wn + nt * 16 + l15;
        bvv[nt] = bias[ncols[nt]];
    }
    #pragma unroll
    for (int mt = 0; mt < 4; ++mt)
        #pragma unroll
        for (int r = 0; r < 4; ++r) {
            size_t m = row0 + wm + mt * 16 + quad * 4 + r;
            #pragma unroll
            for (int nt = 0; nt < 4; ++nt) {
                int n = ncols[nt];
                float v = acc[mt][nt][r] + bvv[nt];
                if (relu) v = fmaxf(v, 0.f);
                if (c_fp32) ((float*)Cp)[m * ldc + n] = v;
                else ((ushort*)Cp)[m * ldc + n] = bfb(v);
            }
        }
}

// ================= conv (K=2, VALID, relu) as MFMA GEMM =================
__global__ __launch_bounds__(256) void convmfma_kernel(const void* __restrict__ X, int x_bf16,
                                                       long xBS,
                                                       const ushort* __restrict__ Ab,
                                                       const float* __restrict__ bias,
                                                       ushort* __restrict__ Y,
                                                       int Cout, int K, int Tout) {
    __shared__ uint4 AsRaw[640];
    __shared__ uint4 BsRaw[640];
    ushort* As = (ushort*)AsRaw;
    ushort* Bs = (ushort*)BsRaw;
    int tid = threadIdx.x, bz = blockIdx.z;
    int row0 = blockIdx.y << 7;
    int lane = tid & 63, wid = tid >> 6;
    int wm = (wid >> 1) * 64, wn = (wid & 1) * 64;
    int l15 = lane & 15, quad = lane >> 4;
    floatx4 acc[4][4];
    #pragma unroll
    for (int i = 0; i < 4; ++i)
        #pragma unroll
        for (int j = 0; j < 4; ++j) acc[i][j] = (floatx4){0.f, 0.f, 0.f, 0.f};
    int am = tid & 127, aseg = tid >> 7;
    int tnext = (am + 1 > 127) ? 127 : am + 1;
    for (int k0 = 0; k0 < K; k0 += 32) {
        {
            const uint4* ap = (const uint4*)(Ab + (size_t)(row0 + am) * K + k0 + aseg * 16);
            uint4* dst = (uint4*)(As + am * 40 + aseg * 16);
            dst[0] = ap[0]; dst[1] = ap[1];
        }
        {
            unsigned r[8];
            if (x_bf16) {
                const ushort* Xb = (const ushort*)X + (size_t)bz * xBS;
                #pragma unroll
                for (int q = 0; q < 8; ++q) {
                    int kk = k0 + aseg * 16 + 2 * q, i = kk >> 1;
                    r[q] = (unsigned)Xb[i * 128 + am] | ((unsigned)Xb[i * 128 + tnext] << 16);
                }
            } else {
                const float* Xf = (const float*)X + (size_t)bz * xBS;
                #pragma unroll
                for (int q = 0; q < 8; ++q) {
                    int kk = k0 + aseg * 16 + 2 * q, i = kk >> 1;
                    r[q] = pk2(Xf[i * 128 + am], Xf[i * 128 + tnext]);
                }
            }
            uint4* dst = (uint4*)(Bs + am * 40 + aseg * 16);
            dst[0] = (uint4){r[0], r[1], r[2], r[3]};
            dst[1] = (uint4){r[4], r[5], r[6], r[7]};
        }
        __syncthreads();
        bf16x8 af[4], bfv[4];
        #pragma unroll
        for (int mt = 0; mt < 4; ++mt)
            af[mt] = __builtin_bit_cast(bf16x8, *(const uint4*)(As + (wm + mt * 16 + l15) * 40 + quad * 8));
        #pragma unroll
        for (int nt = 0; nt < 4; ++nt)
            bfv[nt] = __builtin_bit_cast(bf16x8, *(const uint4*)(Bs + (wn + nt * 16 + l15) * 40 + quad * 8));
        #pragma unroll
        for (int mt = 0; mt < 4; ++mt)
            #pragma unroll
            for (int nt = 0; nt < 4; ++nt)
                acc[mt][nt] = __builtin_amdgcn_mfma_f32_16x16x32_bf16(af[mt], bfv[nt], acc[mt][nt], 0, 0, 0);
        __syncthreads();
    }
    #pragma unroll
    for (int mt = 0; mt < 4; ++mt)
        #pragma unroll
        for (int r = 0; r < 4; ++r) {
            int m = row0 + wm + mt * 16 + quad * 4 + r;
            float bv = bias[m];
            #pragma unroll
            for (int nt = 0; nt < 4; ++nt) {
                int col = wn + nt * 16 + l15;
                float v = fmaxf(acc[mt][nt][r] + bv, 0.f);
                if (col >= Tout) v = 0.f;
                Y[((size_t)bz * Cout + m) * 128 + col] = bfb(v);
            }
        }
}

// ================= class head + CE (MFMA, 16 rows/block) =================
__global__ __launch_bounds__(256) void ce_kernel(const ushort* __restrict__ hx,
                                                 const ushort* __restrict__ Wt,
                                                 const float* __restrict__ bfcx,
                                                 const float* __restrict__ x,
                                                 float* __restrict__ out_class,
                                                 double* __restrict__ acc_ce,
                                                 int row0) {
    __shared__ ushort hxb[16 * 264];
    __shared__ float slog[16][144];
    __shared__ float sce[16];
    int tid = threadIdx.x;
    int lbase = blockIdx.x * 16;
    for (int e = tid; e < 512; e += 256) {
        int r = e >> 5, seg = e & 31;
        *(uint4*)(hxb + r * 264 + seg * 8) = *(const uint4*)(hx + (size_t)(lbase + r) * 256 + seg * 8);
    }
    __syncthreads();
    int lane = tid & 63, wid = tid >> 6, l15 = lane & 15, quad = lane >> 4;
    for (int ct = wid; ct < 9; ct += 4) {
        floatx4 a = (floatx4){0.f, 0.f, 0.f, 0.f};
        #pragma unroll
        for (int k0 = 0; k0 < 8; ++k0) {
            bf16x8 af = __builtin_bit_cast(bf16x8, *(const uint4*)(hxb + l15 * 264 + k0 * 32 + quad * 8));
            bf16x8 bfr = __builtin_bit_cast(bf16x8, *(const uint4*)(Wt + (size_t)(ct * 16 + l15) * 256 + k0 * 32 + quad * 8));
            a = __builtin_amdgcn_mfma_f32_16x16x32_bf16(af, bfr, a, 0, 0, 0);
        }
        int col = ct * 16 + l15;
        float bv = (col < CLS) ? bfcx[col] : 0.f;
        #pragma unroll
        for (int r4 = 0; r4 < 4; ++r4) {
            int r = quad * 4 + r4;
            float v = a[r4] + bv;
            slog[r][col] = v;
            if (col < CLS) out_class[(size_t)(row0 + lbase + r) * CLS + col] = v;
        }
    }
    __syncthreads();
    #pragma unroll
    for (int rr = 0; rr < 4; ++rr) {
        int r = wid * 4 + rr;
        float m = -1e30f;
        for (int j = lane; j < CLS; j += 64) m = fmaxf(m, slog[r][j]);
        #pragma unroll
        for (int o = 32; o > 0; o >>= 1) m = fmaxf(m, __shfl_xor(m, o));
        float s = 0.f;
        for (int j = lane; j < CLS; j += 64) s += expf(slog[r][j] - m);
        #pragma unroll
        for (int o = 32; o > 0; o >>= 1) s += __shfl_xor(s, o);
        if (lane == 0) {
            size_t grow = (size_t)row0 + lbase + r;
            float aa = x[grow * Dd + 0];
            float ss = x[grow * Dd + 1];
            int mapping = (int)((ss - 1.f) * 20.f + (aa - 1.f));
            int idx = mapping > 0 ? mapping : 0;
            float ce = -(slog[r][idx] - m - logf(s));
            sce[r] = (mapping < 0) ? 0.f : ce;
        }
    }
    __syncthreads();
    if (tid == 0) {
        float t = 0.f;
        #pragma unroll
        for (int r = 0; r < 16; ++r) t += sce[r];
        atomicAdd(acc_ce, (double)t);
    }
}

// ================= atom head + MSE (64 rows/block, 1 atomic/block) =================
__global__ __launch_bounds__(256) void atom_kernel(const ushort* __restrict__ ha,
                                                   const float* __restrict__ Wfca,
                                                   const float* __restrict__ bfca,
                                                   const float* __restrict__ x,
                                                   float* __restrict__ out_atom,
                                                   double* __restrict__ acc_mse,
                                                   int row0) {
    __shared__ double sred[4];
    int tid = threadIdx.x;
    int wid = tid >> 6, lane = tid & 63;
    int rowblk = blockIdx.x * 64;
    double msum = 0.0;
    for (int rr = 0; rr < 16; ++rr) {
        int lrow = rowblk + wid * 16 + rr;
        size_t grow = (size_t)row0 + lrow;
        float acc[5] = {};
        for (int k = lane; k < 256; k += 64) {
            float hv = fbf(ha[(size_t)lrow * Hh + k]);
            #pragma unroll
            for (int o = 0; o < 5; ++o) acc[o] = fmaf(hv, Wfca[k * 5 + o], acc[o]);
        }
        #pragma unroll
        for (int o = 0; o < 5; ++o)
            #pragma unroll
            for (int s = 32; s > 0; s >>= 1) acc[o] += __shfl_xor(acc[o], s);
        if (lane == 0) {
            float ms = 0.f;
            #pragma unroll
            for (int o = 0; o < 5; ++o) {
                float v = acc[o] + bfca[o];
                out_atom[grow * 5 + o] = v;
                float d = v - x[grow * Dd + 5 + o];
                ms += d * d;
            }
            msum += (double)ms;
        }
    }
    if (lane == 0) sred[wid] = msum;
    __syncthreads();
    if (tid == 0) atomicAdd(acc_mse, sred[0] + sred[1] + sred[2] + sred[3]);
}

// ========== BCE over out_adj (row-structured, abits bitmask, fast math) ==========
// 1024 blocks x 32 rows; thread t handles cols t and t+256 of each row.
__global__ __launch_bounds__(256) void bce2_kernel(const float* __restrict__ out_adj,
                                                   const ushort* __restrict__ abits,
                                                   const int* __restrict__ nmask,
                                                   double* __restrict__ acc_bce) {
    __shared__ int smn[32];
    __shared__ float sred[4];
    int tid = threadIdx.x;
    int rowbase = blockIdx.x * 32;
    int gb = rowbase >> 9;                      // 32 | 512 -> constant per block
    if (tid < 32) smn[tid] = nmask[rowbase + tid];
    int j0 = tid, j1 = tid + 256;
    int cm0 = nmask[gb * 512 + j0];
    int cm1 = nmask[gb * 512 + j1];
    __syncthreads();
    int l15 = tid & 15;
    float bsum = 0.f;
    for (int r = 0; r < 32; ++r) {
        size_t grow = (size_t)(rowbase + r);
        int n = (int)(grow & 511);
        int mn = smn[r];
        const float* lrow = out_adj + grow * 512;
        const ushort* wrow = abits + grow * 32;
        float l0 = lrow[j0];
        float l1 = lrow[j1];
        int b0 = (wrow[j0 >> 4] >> l15) & 1;
        int b1 = (wrow[j1 >> 4] >> l15) & 1;
        bool ab0 = (mn != 0) && (cm0 != 0) && ((j0 == n) || b0);
        bool ab1 = (mn != 0) && (cm1 != 0) && ((j1 == n) || b1);
        bsum += fmaxf(l0, 0.f) - (ab0 ? l0 : 0.f) + __logf(1.f + __expf(-fabsf(l0)));
        bsum += fmaxf(l1, 0.f) - (ab1 ? l1 : 0.f) + __logf(1.f + __expf(-fabsf(l1)));
    }
    #pragma unroll
    for (int o = 32; o > 0; o >>= 1) bsum += __shfl_xor(bsum, o);
    if ((tid & 63) == 0) sred[tid >> 6] = bsum;
    __syncthreads();
    if (tid == 0) atomicAdd(acc_bce, (double)(sred[0] + sred[1] + sred[2] + sred[3]));
}

// ======== FALLBACK (small ws): R5 fp32 conv + fused adj/BCE ========
__global__ __launch_bounds__(256) void convgemm_kernel(const float* __restrict__ X,
                                                       const float* __restrict__ Wc,
                                                       const float* __restrict__ bias,
                                                       float* __restrict__ Y,
                                                       int Cin, int Tin, int Cout) {
    __shared__ float As[16][68];
    __shared__ float Bs[16][68];
    int K = Cin * 2, Tout = Tin - 1;
    int tid = threadIdx.x, bz = blockIdx.z;
    const float* Xb = X + (size_t)bz * Cin * Tin;
    int m0 = blockIdx.y << 6, col0 = blockIdx.x << 6;
    int tx = tid & 15, ty = tid >> 4;
    float acc[4][4] = {};
    int sm = tid & 63, sks = (tid >> 6) << 2;
    int bkk = tid >> 4, btof = (tid & 15) << 2;
    for (int k0 = 0; k0 < K; k0 += 16) {
        float4 av = *(const float4*)&Wc[(size_t)(m0 + sm) * K + k0 + sks];
        As[sks + 0][sm] = av.x; As[sks + 1][sm] = av.y;
        As[sks + 2][sm] = av.z; As[sks + 3][sm] = av.w;
        {
            int kg = k0 + bkk, i = kg >> 1, par = kg & 1;
            const float* xr = Xb + (size_t)i * Tin;
            #pragma unroll
            for (int j = 0; j < 4; ++j) {
                int t = col0 + btof + j + par;
                if (t > Tin - 1) t = Tin - 1;
                Bs[bkk][btof + j] = xr[t];
            }
        }
        __syncthreads();
        #pragma unroll
        for (int kk = 0; kk < 16; ++kk) {
            float4 a4 = *(const float4*)&As[kk][ty << 2];
            float4 b4 = *(const float4*)&Bs[kk][tx << 2];
            float a[4] = {a4.x, a4.y, a4.z, a4.w};
            float bb[4] = {b4.x, b4.y, b4.z, b4.w};
            #pragma unroll
            for (int i = 0; i < 4; ++i)
                #pragma unroll
                for (int j = 0; j < 4; ++j)
                    acc[i][j] = fmaf(a[i], bb[j], acc[i][j]);
        }
        __syncthreads();
    }
    #pragma unroll
    for (int i = 0; i < 4; ++i) {
        int m = m0 + (ty << 2) + i;
        float bv = bias[m];
        #pragma unroll
        for (int j = 0; j < 4; ++j) {
            int col = col0 + (tx << 2) + j;
            if (col < Tout)
                Y[((size_t)bz * Cout + m) * Tout + col] = fmaxf(acc[i][j] + bv, 0.f);
        }
    }
}

__global__ __launch_bounds__(256) void adjbce_kernel(const float* __restrict__ c2,
                                                     const float* __restrict__ Wfcj,
                                                     const float* __restrict__ bfcj,
                                                     const float* __restrict__ adj,
                                                     const int* __restrict__ nmask,
                                                     float* __restrict__ out_adj,
                                                     double* __restrict__ acc_bce,
                                                     int b0) {
    __shared__ float cs[8][126];
    __shared__ int smn[8];
    __shared__ float sred[4];
    int tid = threadIdx.x;
    int lbase = blockIdx.x * 8;
    size_t growbase = (size_t)b0 * Nn + lbase;
    int gb = (int)(growbase >> 9);
    for (int e = tid; e < 8 * 126; e += 256) {
        int r = e / 126, k = e - r * 126;
        cs[r][k] = c2[(size_t)(lbase + r) * 126 + k];
    }
    if (tid < 8) smn[tid] = nmask[growbase + tid];
    __syncthreads();
    int j0 = tid, j1 = tid + 256;
    float l0[8], l1[8];
    float bj0 = bfcj[j0], bj1 = bfcj[j1];
    #pragma unroll
    for (int r = 0; r < 8; ++r) { l0[r] = bj0; l1[r] = bj1; }
    for (int k = 0; k < 126; ++k) {
        float w0 = Wfcj[k * Nn + j0];
        float w1 = Wfcj[k * Nn + j1];
        #pragma unroll
        for (int r = 0; r < 8; ++r) {
            float cv = cs[r][k];
            l0[r] = fmaf(cv, w0, l0[r]);
            l1[r] = fmaf(cv, w1, l1[r]);
        }
    }
    int cm0 = nmask[(size_t)(gb << 9) + j0];
    int cm1 = nmask[(size_t)(gb << 9) + j1];
    float bsum = 0.f;
    #pragma unroll
    for (int r = 0; r < 8; ++r) {
        size_t grow = growbase + r;
        int n = (int)(grow & 511);
        int mn = smn[r];
        float a0 = adj[grow * Nn + j0];
        float a1 = adj[grow * Nn + j1];
        out_adj[grow * Nn + j0] = l0[r];
        out_adj[grow * Nn + j1] = l1[r];
        bool ab0 = (mn != 0) && (cm0 != 0) && ((j0 == n) || (a0 > 0.f));
        bool ab1 = (mn != 0) && (cm1 != 0) && ((j1 == n) || (a1 > 0.f));
        bsum += fmaxf(l0[r], 0.f) - (ab0 ? l0[r] : 0.f) + log1pf(expf(-fabsf(l0[r])));
        bsum += fmaxf(l1[r], 0.f) - (ab1 ? l1[r] : 0.f) + log1pf(expf(-fabsf(l1[r])));
    }
    #pragma unroll
    for (int o = 32; o > 0; o >>= 1) bsum += __shfl_xor(bsum, o);
    if ((tid & 63) == 0) sred[tid >> 6] = bsum;
    __syncthreads();
    if (tid == 0) atomicAdd(acc_bce, (double)(sred[0] + sred[1] + sred[2] + sred[3]));
}

// ================= final loss =================
__global__ void loss_kernel(const double* __restrict__ acc, float* __restrict__ out) {
    double ce  = acc[0] / 32768.0;
    double bce = acc[1] / 16777216.0;
    double mse = acc[2] / 163840.0;
    double kl  = -0.5 * acc[3];
    double bm = (mse != 0.0) ? fabs(ce + bce) : 0.0;   // beta*mse
    out[0] = (float)(ce + bm + bce + 1e-3 * kl);
}

extern "C" void kernel_launch(void* const* d_in, const int* in_sizes, int n_in,
                              void* d_out, int out_size, void* d_ws, size_t ws_size,
                              hipStream_t stream) {
    const float* x      = (const float*)d_in[0];
    const float* adj    = (const float*)d_in[1];
    const int*   nmask  = (const int*)d_in[2];
    const float* eps    = (const float*)d_in[3];
    const float* W_rel  = (const float*)d_in[4];
    const float* b_rel  = (const float*)d_in[5];
    const float* W_root = (const float*)d_in[6];
    const float* W_mu   = (const float*)d_in[7];
    const float* b_mu   = (const float*)d_in[8];
    const float* W_lv   = (const float*)d_in[9];
    const float* b_lv   = (const float*)d_in[10];
    const float* Wx1    = (const float*)d_in[11];
    const float* bx1    = (const float*)d_in[12];
    const float* Wx2    = (const float*)d_in[13];
    const float* bx2    = (const float*)d_in[14];
    const float* Wx3    = (const float*)d_in[15];
    const float* bx3    = (const float*)d_in[16];
    const float* Wa1    = (const float*)d_in[17];
    const float* ba1    = (const float*)d_in[18];
    const float* Wa2    = (const float*)d_in[19];
    const float* ba2    = (const float*)d_in[20];
    const float* Wa3    = (const float*)d_in[21];
    const float* ba3    = (const float*)d_in[22];
    const float* Wc1    = (const float*)d_in[23];
    const float* bc1    = (const float*)d_in[24];
    const float* Wc2    = (const float*)d_in[25];
    const float* bc2    = (const float*)d_in[26];
    const float* W_fcx  = (const float*)d_in[27];
    const float* b_fcx  = (const float*)d_in[28];
    const float* W_fca  = (const float*)d_in[29];
    const float* b_fca  = (const float*)d_in[30];
    const float* W_fcj  = (const float*)d_in[31];
    const float* b_fcj  = (const float*)d_in[32];

    float* out = (float*)d_out;
    char* region = (char*)(out + OUT_ADJ);
    ushort* t1 = (ushort*)(region + T1_OFF);
    ushort* t2 = (ushort*)(region + T2_OFF);
    ushort* hx = (ushort*)(region + HX_OFF);
    float*  Z  = (float*)(region + Z_OFF);
    float*  axs_g = (float*)(region + AXS_OFF);

    // MLP-phase weights in region (dead before conv phase)
    ushort* wt_x1  = (ushort*)(region + WT_OFF);
    ushort* wt_x2  = wt_x1 + 65536;
    ushort* wt_x3  = wt_x2 + 262144;
    ushort* wt_a1  = wt_x3 + 131072;
    ushort* wt_a2  = wt_a1 + 65536;
    ushort* wt_a3  = wt_a2 + 262144;
    ushort* wt_mu  = wt_a3 + 131072;
    ushort* wt_lv  = wt_mu + 32768;
    ushort* wt_fcx = wt_lv + 32768;
    ushort* wt_enc = wt_fcx + 36864;       // [256][64] bf16 hi|lo combined W_rel/W_root

    // conv-phase weights + buffers in d_ws
    double* acc = (double*)d_ws;
    ushort* wc1b   = (ushort*)((char*)d_ws + 256);
    ushort* wc2b   = wc1b + 262144;
    ushort* wt_fcj = wc2b + 262144;
    // abits (2 MB) lives in d_ws so the out_adj write can't clobber it (race-safe).
    ushort* abits_ws = (ushort*)((char*)d_ws + 1179904);
    char* convbuf = (char*)d_ws + 1179904 + 2097152;
    bool fastConv = ws_size >= (size_t)1179904 + 2097152 + 196608;
    // fallback: abits unread -> park it in the region gap (clobbered later, harmless)
    ushort* abits = fastConv ? abits_ws : (ushort*)(region + ABITS_FB_OFF);

    hipMemsetAsync(d_ws, 0, 256, stream);

    // ---- prep table ----
    PTable tab;
    int t0 = 0;
    auto setT = [&](int i, const float* s, ushort* d, int R, int C, int Cp, int Kp) {
        tab.d[i] = {s, d, R, C, Cp, Kp, t0, 0};
        t0 += ((Cp + 31) / 32) * ((Kp + 31) / 32);
    };
    setT(0, Wx1, wt_x1, 128, 512, 512, 128);
    setT(1, Wx2, wt_x2, 512, 512, 512, 512);
    setT(2, Wx3, wt_x3, 512, 256, 256, 512);
    setT(3, Wa1, wt_a1, 128, 512, 512, 128);
    setT(4, Wa2, wt_a2, 512, 512, 512, 512);
    setT(5, Wa3, wt_a3, 512, 256, 256, 512);
    setT(6, W_mu, wt_mu, 256, 128, 128, 256);
    setT(7, W_lv, wt_lv, 256, 128, 128, 256);
    // encoder combined weight [256][64] hi|lo (disjoint strided writes, koff = mode-64)
    setT(8,  W_rel,  wt_enc, 10, 256, 256, 10); tab.d[8].mode  = 64 + 0;    // rel hi  k 0..9
    setT(9,  W_root, wt_enc, 10, 256, 256, 10); tab.d[9].mode  = 64 + 10;   // root hi k 10..19
    setT(10, W_rel,  wt_enc, 0,  0,   256, 12); tab.d[10].mode = 64 + 20;   // zeros   k 20..31
    setT(11, W_rel,  wt_enc, 10, 256, 256, 10); tab.d[11].mode = 64 + 32;   // rel lo  k 32..41
    setT(12, W_root, wt_enc, 10, 256, 256, 10); tab.d[12].mode = 64 + 42;   // root lo k 42..51
    setT(13, W_rel,  wt_enc, 0,  0,   256, 12); tab.d[13].mode = 64 + 52;   // zeros   k 52..63
    setT(14, W_fcx, wt_fcx, 256, 140, 144, 256);
    int t_nofcj = t0;
    setT(15, W_fcj, wt_fcj, 126, 512, 512, 128);
    tab.d[16] = {Wc1, wc1b, 262144, 0, 0, 0, t0, 1}; t0 += 32;
    tab.d[17] = {Wc2, wc2b, 262144, 0, 0, 0, t0, 1}; t0 += 32;
    prep_kernel<<<fastConv ? t0 : t_nofcj, 256, 0, stream>>>(tab);

    // ---- encoder: memory-heavy agg (+ adj>0 bitpack) + all-MFMA enc2 ----
    agg_kernel<<<ROWS / 16, 256, 0, stream>>>(adj, x, axs_g, abits);
    enc2_kernel<<<ROWS / 16, 256, 0, stream>>>(axs_g, wt_enc, b_rel, nmask,
                                               wt_mu, b_mu, wt_lv, b_lv, eps, Z, acc + 3);

    // ---- MLP chains ----
    for (int c = 0; c < 2; ++c) {
        int r0 = c * CH;
        mgemm_kernel<<<dim3(4, 128), 256, 0, stream>>>(Z + (size_t)r0 * Ll, 0, wt_x1, bx1, t1, 0, 512, 128, 512, 1);
        mgemm_kernel<<<dim3(4, 128), 256, 0, stream>>>(t1, 1, wt_x2, bx2, t2, 0, 512, 512, 512, 1);
        mgemm_kernel<<<dim3(2, 128), 256, 0, stream>>>(t2, 1, wt_x3, bx3, hx, 0, 256, 512, 256, 0);
        ce_kernel<<<CH / 16, 256, 0, stream>>>(hx, wt_fcx, b_fcx, x, out + OUT_CLASS, acc + 0, r0);
    }
    for (int c = 0; c < 2; ++c) {
        int r0 = c * CH;
        mgemm_kernel<<<dim3(4, 128), 256, 0, stream>>>(Z + (size_t)r0 * Ll, 0, wt_a1, ba1, t1, 0, 512, 128, 512, 1);
        mgemm_kernel<<<dim3(4, 128), 256, 0, stream>>>(t1, 1, wt_a2, ba2, t2, 0, 512, 512, 512, 1);
        mgemm_kernel<<<dim3(2, 128), 256, 0, stream>>>(t2, 1, wt_a3, ba3, hx, 0, 256, 512, 256, 0);
        atom_kernel<<<CH / 64, 256, 0, stream>>>(hx, W_fca, b_fca, x, out + OUT_ATOM, acc + 2, r0);
    }

    // ---- conv path + adj head + dedicated BCE pass (abits-based) ----
    if (fastConv) {
        size_t avail = ws_size - 1179904 - 2097152;
        int NB = 64;
        while (NB > 1 && (size_t)NB * 196608 > avail) NB >>= 1;
        ushort* c1 = (ushort*)convbuf;
        ushort* c2 = c1 + (size_t)NB * 32768;
        for (int b0 = 0; b0 < 64; b0 += NB) {
            convmfma_kernel<<<dim3(1, 2, NB), 256, 0, stream>>>(Z + (size_t)b0 * 65536, 0, 65536,
                                                               wc1b, bc1, c1, 256, 1024, 127);
            convmfma_kernel<<<dim3(1, 4, NB), 256, 0, stream>>>(c1, 1, 32768,
                                                               wc2b, bc2, c2, 512, 512, 126);
            mgemm_kernel<<<dim3(4, NB * 4), 256, 0, stream>>>(c2, 1, wt_fcj, b_fcj,
                                                              out + OUT_ADJ + (size_t)b0 * 262144, 1,
                                                              512, 128, 512, 0);
        }
        bce2_kernel<<<1024, 256, 0, stream>>>(out + OUT_ADJ, abits, nmask, acc + 1);
    } else {
        size_t avail = (ws_size > 256) ? ws_size - 256 : 0;
        int NB = 64;
        while (NB > 1 && (size_t)NB * 388096 > avail) NB >>= 1;
        float* c1 = (float*)((char*)d_ws + 256);
        float* c2 = (float*)((char*)d_ws + 256 + (size_t)NB * 256 * 127 * 4);
        for (int b0 = 0; b0 < 64; b0 += NB) {
            convgemm_kernel<<<dim3(2, 4, NB), 256, 0, stream>>>(Z + (size_t)b0 * 65536, Wc1, bc1, c1, 512, 128, 256);
            convgemm_kernel<<<dim3(2, 8, NB), 256, 0, stream>>>(c1, Wc2, bc2, c2, 256, 127, 512);
            adjbce_kernel<<<NB * Nn / 8, 256, 0, stream>>>(c2, W_fcj, b_fcj, adj, nmask,
                                                           out + OUT_ADJ, acc + 1, b0);
        }
    }

    loss_kernel<<<1, 1, 0, stream>>>(acc, out);
}

// Round 14
// 747.054 us; speedup vs baseline: 1.0237x; 1.0237x over previous
//
#include <hip/hip_runtime.h>
#include <hip/hip_bf16.h>
#include <cstdint>

using bf16x8 = __attribute__((ext_vector_type(8))) __bf16;
using floatx4 = __attribute__((ext_vector_type(4))) float;
typedef unsigned short ushort;

#define Nn  512
#define Dd  10
#define Hh  256
#define Ll  128
#define CLS 140
#define ROWS 32768
#define CH  16384

// out buffer (fp32) element offsets
#define OUT_CLASS 1ull
#define OUT_ATOM  4587521ull
#define OUT_ADJ   4751361ull

// byte offsets inside dead out_adj region (67,108,864 B, base ≡ 4 mod 16)
#define T1_OFF 12ull
#define T2_OFF (12ull + 16777216ull)
#define HX_OFF (12ull + 33554432ull)
#define WT_OFF 41943068ull          // region+WT_OFF ≡ 0 mod 16
#define AXS_OFF 45088780ull         // region+AXS_OFF ≡ 0 mod 16
#define ABITS_FB_OFF 47710224ull    // fallback-only abits (unused there; clobber-safe)
#define Z_OFF  50331644ull          // region+Z_OFF ≡ 0 mod 16

static __device__ __forceinline__ ushort bfb(float v) {
    __hip_bfloat16 h = __float2bfloat16(v);
    return *reinterpret_cast<ushort*>(&h);
}
static __device__ __forceinline__ float fbf(ushort u) {
    __hip_bfloat16 h = *reinterpret_cast<__hip_bfloat16*>(&u);
    return __bfloat162float(h);
}
static __device__ __forceinline__ unsigned pk2(float a, float b) {
    return (unsigned)bfb(a) | ((unsigned)bfb(b) << 16);
}

// ================= prep: weight convert/transpose to bf16 =================
// mode 0: transpose convert dst[n*Kp+k]
// mode 1: plain convert
// mode >= 64: strided write into [Cp][64] hi|lo layout: dst[n*64 + (mode-64) + k];
//             (mode-64) >= 32 -> store lo part: bf16(v - fbf(bf16(v)))
struct PDesc { const float* src; ushort* dst; int srcR, srcC, Cp, Kp, tile0, mode; };
struct PTable { PDesc d[18]; };

__global__ __launch_bounds__(256) void prep_kernel(PTable tab) {
    __shared__ float tile[32][33];
    int bt = blockIdx.x, tid = threadIdx.x;
    int di = 0;
    #pragma unroll
    for (int i = 1; i < 18; ++i) if (bt >= tab.d[i].tile0) di = i;
    PDesc d = tab.d[di];
    int lt = bt - d.tile0;
    if (d.mode == 1) {  // plain convert
        long base = (long)lt * 8192;
        const float* s = d.src;
        ushort* o = d.dst;
        for (int i = tid; i < 2048; i += 256) {
            long idx = base + (long)i * 4;
            float4 v = *(const float4*)&s[idx];
            unsigned u0 = pk2(v.x, v.y), u1 = pk2(v.z, v.w);
            *(uint2*)&o[idx] = (uint2){u0, u1};
        }
        return;
    }
    int tilesK = (d.Kp + 31) >> 5;
    int k0 = (lt % tilesK) << 5, n0 = (lt / tilesK) << 5;
    int tx = tid & 31, ty = tid >> 5;
    for (int ky = ty; ky < 32; ky += 8) {
        int k = k0 + ky, n = n0 + tx;
        float v = (k < d.srcR && n < d.srcC) ? d.src[(size_t)k * d.srcC + n] : 0.f;
        tile[ky][tx] = v;
    }
    __syncthreads();
    for (int ny = ty; ny < 32; ny += 8) {
        int n = n0 + ny, k = k0 + tx;
        if (n < d.Cp && k < d.Kp) {
            float v = tile[tx][ny];
            if (d.mode >= 64) {
                int koff = d.mode - 64;
                ushort u;
                if (koff >= 32) u = bfb(v - fbf(bfb(v)));   // lo residual
                else u = bfb(v);                            // hi
                d.dst[(size_t)n * 64 + koff + k] = u;
            } else {
                d.dst[(size_t)n * d.Kp + k] = bfb(v);
            }
        }
    }
}

// ================= encoder stage 1: adj aggregation + adj>0 bitpack =================
// float4 adj loads (16B/lane). Lane l16 handles columns 4*l16+64*it+{0..3}.
// abits layout unchanged: bit for column c at abits[row*32 + c/16], bit c%16.
__global__ __launch_bounds__(256, 8) void agg_kernel(
    const float* __restrict__ adj, const float* __restrict__ x,
    float* __restrict__ axs_g, ushort* __restrict__ abits)
{
    __shared__ float4 xs4[1536];            // 512 rows x 12 floats (padded)
    float* xs = (float*)xs4;
    int tid = threadIdx.x;
    int rowbase = blockIdx.x * 16;
    int b = rowbase >> 9, rowloc = rowbase & 511;
    const float* xb = x + (size_t)b * 5120;
    for (int e = tid; e < 6144; e += 256) {
        int j = e / 12, d = e - j * 12;
        xs[e] = (d < 10) ? xb[j * 10 + d] : 0.f;
    }
    __syncthreads();
    int g = tid >> 4, l16 = tid & 15;
    int row = rowbase + g;
    const float4* arow4 = (const float4*)(adj + (size_t)row * Nn);
    float accv[10] = {};
    float deg = 0.f;
    #define ACCUM(a_, j_) do { float a = (a_); if (a != 0.f) {               \
        const float4 v0 = xs4[(j_) * 3 + 0];                                 \
        const float4 v1 = xs4[(j_) * 3 + 1];                                 \
        const float4 v2 = xs4[(j_) * 3 + 2];                                 \
        deg += a;                                                            \
        accv[0] += a * v0.x; accv[1] += a * v0.y;                            \
        accv[2] += a * v0.z; accv[3] += a * v0.w;                            \
        accv[4] += a * v1.x; accv[5] += a * v1.y;                            \
        accv[6] += a * v1.z; accv[7] += a * v1.w;                            \
        accv[8] += a * v2.x; accv[9] += a * v2.y; } } while (0)
    #pragma unroll
    for (int it = 0; it < 8; ++it) {
        float4 av = arow4[l16 + (it << 4)];
        int nib = ((av.x > 0.f) ? 1 : 0) | ((av.y > 0.f) ? 2 : 0) |
                  ((av.z > 0.f) ? 4 : 0) | ((av.w > 0.f) ? 8 : 0);
        int n2 = nib | (__shfl_xor(nib, 1) << 4);
        int n4 = n2 | (__shfl_xor(n2, 2) << 8);
        if ((l16 & 3) == 0) abits[(size_t)row * 32 + it * 4 + (l16 >> 2)] = (ushort)n4;
        int jb = 4 * l16 + (it << 6);
        ACCUM(av.x, jb + 0);
        ACCUM(av.y, jb + 1);
        ACCUM(av.z, jb + 2);
        ACCUM(av.w, jb + 3);
    }
    #undef ACCUM
    #pragma unroll
    for (int o = 8; o > 0; o >>= 1) {
        deg += __shfl_xor(deg, o);
        #pragma unroll
        for (int d = 0; d < 10; ++d) accv[d] += __shfl_xor(accv[d], o);
    }
    float* orow = axs_g + (size_t)row * 20;
    if (l16 == 0) {
        float dg = fmaxf(deg, 1.f);
        #pragma unroll
        for (int d = 0; d < 10; ++d) orow[d] = accv[d] / dg;
    }
    if (l16 < 10) orow[10 + l16] = xs[(rowloc + g) * 12 + l16];
}

// ================= encoder stage 2: all-MFMA h -> mu/lv -> z + KL =================
// (r10 structure) Phase 3 stores mu/lv to LDS; phase 4 does z + KL coalesced.
// zbf16 != 0: write Z as bf16 (same __float2bfloat16 bits all consumers produced
// internally before -> bit-identical downstream, half the write traffic).
__global__ __launch_bounds__(256, 4) void enc2_kernel(
    const float* __restrict__ axs_g,
    const ushort* __restrict__ Wenc,       // [256][64] bf16: k<10 rel-hi, 10..19 root-hi, 32..41 rel-lo, 42..51 root-lo, rest 0
    const float* __restrict__ brel, const int* __restrict__ nmask,
    const ushort* __restrict__ Wtmu, const float* __restrict__ bmu,
    const ushort* __restrict__ Wtlv, const float* __restrict__ blv,
    const float* __restrict__ eps, void* __restrict__ Zout, int zbf16,
    double* __restrict__ acc_kl)
{
    __shared__ float sml[4096];             // [2][16][128] mu/lv (16 KB)
    __shared__ uint4 axsbRaw[160];          // 16 x 80 ushorts (hi at d<20, lo at 40..59)
    __shared__ uint4 hsbRaw[528];           // 16 x 264 ushorts
    __shared__ int smask[16];
    __shared__ float skred[4];
    ushort* axsb = (ushort*)axsbRaw;
    ushort* hsb = (ushort*)hsbRaw;
    int tid = threadIdx.x;
    int rowbase = blockIdx.x * 16;
    size_t abase = (size_t)rowbase * 20;

    // phase A: stage axs as split-bf16 A fragments
    for (int e = tid; e < 1280; e += 256) {
        int r = e / 80, d = e - r * 80;
        ushort u = 0;
        if (d < 20) {
            u = bfb(axs_g[abase + r * 20 + d]);
        } else if (d >= 40 && d < 60) {
            float v = axs_g[abase + r * 20 + d - 40];
            u = bfb(v - fbf(bfb(v)));
        }
        axsb[e] = u;
    }
    if (tid < 16) smask[tid] = nmask[rowbase + tid];
    __syncthreads();

    int lane = tid & 63, wid = tid >> 6;
    int l15 = lane & 15, quad = lane >> 4;

    // phase 2: h via MFMA (M=16, N=256, K=32), split hi/lo for fp32 accuracy
    {
        bf16x8 ah = __builtin_bit_cast(bf16x8, *(const uint4*)(axsb + l15 * 80 + quad * 8));
        bf16x8 al = __builtin_bit_cast(bf16x8, *(const uint4*)(axsb + l15 * 80 + 40 + quad * 8));
        #pragma unroll
        for (int i = 0; i < 4; ++i) {
            int ct = wid * 4 + i;
            int col = ct * 16 + l15;
            bf16x8 bh = __builtin_bit_cast(bf16x8, *(const uint4*)(Wenc + (size_t)col * 64 + quad * 8));
            bf16x8 blo = __builtin_bit_cast(bf16x8, *(const uint4*)(Wenc + (size_t)col * 64 + 32 + quad * 8));
            floatx4 a = (floatx4){0.f, 0.f, 0.f, 0.f};
            a = __builtin_amdgcn_mfma_f32_16x16x32_bf16(al, bh, a, 0, 0, 0);
            a = __builtin_amdgcn_mfma_f32_16x16x32_bf16(ah, blo, a, 0, 0, 0);
            a = __builtin_amdgcn_mfma_f32_16x16x32_bf16(ah, bh, a, 0, 0, 0);
            float bb = brel[col];
            #pragma unroll
            for (int r4 = 0; r4 < 4; ++r4) {
                int row = quad * 4 + r4;
                float v = a[r4] + bb;
                v = (smask[row] != 0) ? fmaxf(v, 0.f) : 0.f;
                hsb[row * 264 + col] = bfb(v);
            }
        }
    }
    __syncthreads();

    // phase 3: mu/lv MFMA -> sml (fp32, bit-preserving)
    #pragma unroll
    for (int i = 0; i < 2; ++i) {
        int ct = wid * 2 + i;
        int col = ct * 16 + l15;
        floatx4 amu = (floatx4){0.f, 0.f, 0.f, 0.f};
        floatx4 alv = (floatx4){0.f, 0.f, 0.f, 0.f};
        #pragma unroll
        for (int k0 = 0; k0 < 8; ++k0) {
            bf16x8 af = __builtin_bit_cast(bf16x8, *(const uint4*)(hsb + l15 * 264 + k0 * 32 + quad * 8));
            bf16x8 bm = __builtin_bit_cast(bf16x8, *(const uint4*)(Wtmu + (size_t)col * 256 + k0 * 32 + quad * 8));
            bf16x8 bl = __builtin_bit_cast(bf16x8, *(const uint4*)(Wtlv + (size_t)col * 256 + k0 * 32 + quad * 8));
            amu = __builtin_amdgcn_mfma_f32_16x16x32_bf16(af, bm, amu, 0, 0, 0);
            alv = __builtin_amdgcn_mfma_f32_16x16x32_bf16(af, bl, alv, 0, 0, 0);
        }
        float bmv = bmu[col], blv_ = blv[col];
        #pragma unroll
        for (int r4 = 0; r4 < 4; ++r4) {
            int row = quad * 4 + r4;
            sml[row * 128 + col] = amu[r4] + bmv;
            sml[2048 + row * 128 + col] = alv[r4] + blv_;
        }
    }
    __syncthreads();

    // phase 4: z + KL, fully coalesced (thread t -> f4 idx t and t+256)
    {
        float kt = 0.f;
        const float4* ep4 = (const float4*)(eps + (size_t)rowbase * Ll);
        const float4* mu4 = (const float4*)sml;
        const float4* lv4 = (const float4*)(sml + 2048);
        #pragma unroll
        for (int i = 0; i < 2; ++i) {
            int e4 = tid + i * 256;
            float4 ee = ep4[e4];
            float4 mu = mu4[e4];
            float4 lv = lv4[e4];
            float4 zz;
            zz.x = mu.x + ee.x * expf(0.5f * lv.x);
            zz.y = mu.y + ee.y * expf(0.5f * lv.y);
            zz.z = mu.z + ee.z * expf(0.5f * lv.z);
            zz.w = mu.w + ee.w * expf(0.5f * lv.w);
            if (zbf16) {
                ushort* Zb = (ushort*)Zout + (size_t)rowbase * Ll;
                *(uint2*)(Zb + e4 * 4) = (uint2){pk2(zz.x, zz.y), pk2(zz.z, zz.w)};
            } else {
                float4* z4 = (float4*)Zout + (size_t)rowbase * (Ll / 4);
                z4[e4] = zz;
            }
            kt += 1.f + lv.x - mu.x * mu.x - expf(lv.x);
            kt += 1.f + lv.y - mu.y * mu.y - expf(lv.y);
            kt += 1.f + lv.z - mu.z * mu.z - expf(lv.z);
            kt += 1.f + lv.w - mu.w * mu.w - expf(lv.w);
        }
        #pragma unroll
        for (int o = 32; o > 0; o >>= 1) kt += __shfl_xor(kt, o);
        if (lane == 0) skred[wid] = kt;
    }
    __syncthreads();
    if (tid == 0) atomicAdd(acc_kl, (double)(skred[0] + skred[1] + skred[2] + skred[3]));
}

// ================= unified MFMA GEMM: C = relu?(A @ Bt^T + bias) =================
// A row-major [M][K] fp32 or bf16; Bt bf16 [N][K]; C bf16 or fp32, row stride ldc.
// XCD-aware block swizzle (bijective, requires gridDim.x*gridDim.y % 8 == 0).
__global__ __launch_bounds__(256) void mgemm_kernel(const void* __restrict__ A, int a_bf16,
                                                    const ushort* __restrict__ Bt,
                                                    const float* __restrict__ bias,
                                                    void* __restrict__ Cp, int c_fp32,
                                                    int N, int K, int ldc, int relu) {
    __shared__ uint4 AsRaw[640];
    __shared__ uint4 BsRaw[640];
    ushort* As = (ushort*)AsRaw;
    ushort* Bs = (ushort*)BsRaw;
    int tid = threadIdx.x;
    int nwg = gridDim.x * gridDim.y;
    int bid = blockIdx.y * gridDim.x + blockIdx.x;
    int swz = (bid & 7) * (nwg >> 3) + (bid >> 3);
    int row0 = (swz / gridDim.x) << 7, col0 = (swz % gridDim.x) << 7;
    int lane = tid & 63, wid = tid >> 6;
    int wm = (wid >> 1) * 64, wn = (wid & 1) * 64;
    int l15 = lane & 15, quad = lane >> 4;
    floatx4 acc[4][4];
    #pragma unroll
    for (int i = 0; i < 4; ++i)
        #pragma unroll
        for (int j = 0; j < 4; ++j) acc[i][j] = (floatx4){0.f, 0.f, 0.f, 0.f};
    int am = tid & 127, aseg = tid >> 7;
    for (int k0 = 0; k0 < K; k0 += 32) {
        {
            uint4* dst = (uint4*)(As + am * 40 + aseg * 16);
            if (a_bf16) {
                const uint4* ap = (const uint4*)((const ushort*)A + (size_t)(row0 + am) * K + k0 + aseg * 16);
                dst[0] = ap[0]; dst[1] = ap[1];
            } else {
                const float4* ap = (const float4*)((const float*)A + (size_t)(row0 + am) * K + k0 + aseg * 16);
                float4 f0 = ap[0], f1 = ap[1], f2 = ap[2], f3 = ap[3];
                dst[0] = (uint4){pk2(f0.x, f0.y), pk2(f0.z, f0.w), pk2(f1.x, f1.y), pk2(f1.z, f1.w)};
                dst[1] = (uint4){pk2(f2.x, f2.y), pk2(f2.z, f2.w), pk2(f3.x, f3.y), pk2(f3.z, f3.w)};
            }
        }
        {
            const uint4* bp = (const uint4*)(Bt + (size_t)(col0 + am) * K + k0 + aseg * 16);
            uint4* dst = (uint4*)(Bs + am * 40 + aseg * 16);
            dst[0] = bp[0]; dst[1] = bp[1];
        }
        __syncthreads();
        bf16x8 af[4], bfv[4];
        #pragma unroll
        for (int mt = 0; mt < 4; ++mt)
            af[mt] = __builtin_bit_cast(bf16x8, *(const uint4*)(As + (wm + mt * 16 + l15) * 40 + quad * 8));
        #pragma unroll
        for (int nt = 0; nt < 4; ++nt)
            bfv[nt] = __builtin_bit_cast(bf16x8, *(const uint4*)(Bs + (wn + nt * 16 + l15) * 40 + quad * 8));
        #pragma unroll
        for (int mt = 0; mt < 4; ++mt)
            #pragma unroll
            for (int nt = 0; nt < 4; ++nt)
                acc[mt][nt] = __builtin_amdgcn_mfma_f32_16x16x32_bf16(af[mt], bfv[nt], acc[mt][nt], 0, 0, 0);
        __syncthreads();
    }
    // epilogue: mt,r outer / nt inner (adjacent store chunks per row -> better combining)
    float bvv[4];
    int ncols[4];
    #pragma unroll
    for (int nt = 0; nt < 4; ++nt) {
        ncols[nt] = col0 + wn + nt * 16 + l15;
        bvv[nt] = bias[ncols[nt]];
    }
    #pragma unroll
    for (int mt = 0; mt < 4; ++mt)
        #pragma unroll
        for (int r = 0; r < 4; ++r) {
            size_t m = row0 + wm + mt * 16 + quad * 4 + r;
            #pragma unroll
            for (int nt = 0; nt < 4; ++nt) {
                int n = ncols[nt];
                float v = acc[mt][nt][r] + bvv[nt];
                if (relu) v = fmaxf(v, 0.f);
                if (c_fp32) ((float*)Cp)[m * ldc + n] = v;
                else ((ushort*)Cp)[m * ldc + n] = bfb(v);
            }
        }
}

// ================= conv (K=2, VALID, relu) as MFMA GEMM =================
__global__ __launch_bounds__(256) void convmfma_kernel(const void* __restrict__ X, int x_bf16,
                                                       long xBS,
                                                       const ushort* __restrict__ Ab,
                                                       const float* __restrict__ bias,
                                                       ushort* __restrict__ Y,
                                                       int Cout, int K, int Tout) {
    __shared__ uint4 AsRaw[640];
    __shared__ uint4 BsRaw[640];
    ushort* As = (ushort*)AsRaw;
    ushort* Bs = (ushort*)BsRaw;
    int tid = threadIdx.x, bz = blockIdx.z;
    int row0 = blockIdx.y << 7;
    int lane = tid & 63, wid = tid >> 6;
    int wm = (wid >> 1) * 64, wn = (wid & 1) * 64;
    int l15 = lane & 15, quad = lane >> 4;
    floatx4 acc[4][4];
    #pragma unroll
    for (int i = 0; i < 4; ++i)
        #pragma unroll
        for (int j = 0; j < 4; ++j) acc[i][j] = (floatx4){0.f, 0.f, 0.f, 0.f};
    int am = tid & 127, aseg = tid >> 7;
    int tnext = (am + 1 > 127) ? 127 : am + 1;
    for (int k0 = 0; k0 < K; k0 += 32) {
        {
            const uint4* ap = (const uint4*)(Ab + (size_t)(row0 + am) * K + k0 + aseg * 16);
            uint4* dst = (uint4*)(As + am * 40 + aseg * 16);
            dst[0] = ap[0]; dst[1] = ap[1];
        }
        {
            unsigned r[8];
            if (x_bf16) {
                const ushort* Xb = (const ushort*)X + (size_t)bz * xBS;
                #pragma unroll
                for (int q = 0; q < 8; ++q) {
                    int kk = k0 + aseg * 16 + 2 * q, i = kk >> 1;
                    r[q] = (unsigned)Xb[i * 128 + am] | ((unsigned)Xb[i * 128 + tnext] << 16);
                }
            } else {
                const float* Xf = (const float*)X + (size_t)bz * xBS;
                #pragma unroll
                for (int q = 0; q < 8; ++q) {
                    int kk = k0 + aseg * 16 + 2 * q, i = kk >> 1;
                    r[q] = pk2(Xf[i * 128 + am], Xf[i * 128 + tnext]);
                }
            }
            uint4* dst = (uint4*)(Bs + am * 40 + aseg * 16);
            dst[0] = (uint4){r[0], r[1], r[2], r[3]};
            dst[1] = (uint4){r[4], r[5], r[6], r[7]};
        }
        __syncthreads();
        bf16x8 af[4], bfv[4];
        #pragma unroll
        for (int mt = 0; mt < 4; ++mt)
            af[mt] = __builtin_bit_cast(bf16x8, *(const uint4*)(As + (wm + mt * 16 + l15) * 40 + quad * 8));
        #pragma unroll
        for (int nt = 0; nt < 4; ++nt)
            bfv[nt] = __builtin_bit_cast(bf16x8, *(const uint4*)(Bs + (wn + nt * 16 + l15) * 40 + quad * 8));
        #pragma unroll
        for (int mt = 0; mt < 4; ++mt)
            #pragma unroll
            for (int nt = 0; nt < 4; ++nt)
                acc[mt][nt] = __builtin_amdgcn_mfma_f32_16x16x32_bf16(af[mt], bfv[nt], acc[mt][nt], 0, 0, 0);
        __syncthreads();
    }
    #pragma unroll
    for (int mt = 0; mt < 4; ++mt)
        #pragma unroll
        for (int r = 0; r < 4; ++r) {
            int m = row0 + wm + mt * 16 + quad * 4 + r;
            float bv = bias[m];
            #pragma unroll
            for (int nt = 0; nt < 4; ++nt) {
                int col = wn + nt * 16 + l15;
                float v = fmaxf(acc[mt][nt][r] + bv, 0.f);
                if (col >= Tout) v = 0.f;
                Y[((size_t)bz * Cout + m) * 128 + col] = bfb(v);
            }
        }
}

// ================= class head + CE (MFMA, 16 rows/block) =================
__global__ __launch_bounds__(256) void ce_kernel(const ushort* __restrict__ hx,
                                                 const ushort* __restrict__ Wt,
                                                 const float* __restrict__ bfcx,
                                                 const float* __restrict__ x,
                                                 float* __restrict__ out_class,
                                                 double* __restrict__ acc_ce,
                                                 int row0) {
    __shared__ ushort hxb[16 * 264];
    __shared__ float slog[16][144];
    __shared__ float sce[16];
    int tid = threadIdx.x;
    int lbase = blockIdx.x * 16;
    for (int e = tid; e < 512; e += 256) {
        int r = e >> 5, seg = e & 31;
        *(uint4*)(hxb + r * 264 + seg * 8) = *(const uint4*)(hx + (size_t)(lbase + r) * 256 + seg * 8);
    }
    __syncthreads();
    int lane = tid & 63, wid = tid >> 6, l15 = lane & 15, quad = lane >> 4;
    for (int ct = wid; ct < 9; ct += 4) {
        floatx4 a = (floatx4){0.f, 0.f, 0.f, 0.f};
        #pragma unroll
        for (int k0 = 0; k0 < 8; ++k0) {
            bf16x8 af = __builtin_bit_cast(bf16x8, *(const uint4*)(hxb + l15 * 264 + k0 * 32 + quad * 8));
            bf16x8 bfr = __builtin_bit_cast(bf16x8, *(const uint4*)(Wt + (size_t)(ct * 16 + l15) * 256 + k0 * 32 + quad * 8));
            a = __builtin_amdgcn_mfma_f32_16x16x32_bf16(af, bfr, a, 0, 0, 0);
        }
        int col = ct * 16 + l15;
        float bv = (col < CLS) ? bfcx[col] : 0.f;
        #pragma unroll
        for (int r4 = 0; r4 < 4; ++r4) {
            int r = quad * 4 + r4;
            float v = a[r4] + bv;
            slog[r][col] = v;
            if (col < CLS) out_class[(size_t)(row0 + lbase + r) * CLS + col] = v;
        }
    }
    __syncthreads();
    #pragma unroll
    for (int rr = 0; rr < 4; ++rr) {
        int r = wid * 4 + rr;
        float m = -1e30f;
        for (int j = lane; j < CLS; j += 64) m = fmaxf(m, slog[r][j]);
        #pragma unroll
        for (int o = 32; o > 0; o >>= 1) m = fmaxf(m, __shfl_xor(m, o));
        float s = 0.f;
        for (int j = lane; j < CLS; j += 64) s += expf(slog[r][j] - m);
        #pragma unroll
        for (int o = 32; o > 0; o >>= 1) s += __shfl_xor(s, o);
        if (lane == 0) {
            size_t grow = (size_t)row0 + lbase + r;
            float aa = x[grow * Dd + 0];
            float ss = x[grow * Dd + 1];
            int mapping = (int)((ss - 1.f) * 20.f + (aa - 1.f));
            int idx = mapping > 0 ? mapping : 0;
            float ce = -(slog[r][idx] - m - logf(s));
            sce[r] = (mapping < 0) ? 0.f : ce;
        }
    }
    __syncthreads();
    if (tid == 0) {
        float t = 0.f;
        #pragma unroll
        for (int r = 0; r < 16; ++r) t += sce[r];
        atomicAdd(acc_ce, (double)t);
    }
}

// ================= atom head + MSE (64 rows/block, 1 atomic/block) =================
__global__ __launch_bounds__(256) void atom_kernel(const ushort* __restrict__ ha,
                                                   const float* __restrict__ Wfca,
                                                   const float* __restrict__ bfca,
                                                   const float* __restrict__ x,
                                                   float* __restrict__ out_atom,
                                                   double* __restrict__ acc_mse,
                                                   int row0) {
    __shared__ double sred[4];
    int tid = threadIdx.x;
    int wid = tid >> 6, lane = tid & 63;
    int rowblk = blockIdx.x * 64;
    double msum = 0.0;
    for (int rr = 0; rr < 16; ++rr) {
        int lrow = rowblk + wid * 16 + rr;
        size_t grow = (size_t)row0 + lrow;
        float acc[5] = {};
        for (int k = lane; k < 256; k += 64) {
            float hv = fbf(ha[(size_t)lrow * Hh + k]);
            #pragma unroll
            for (int o = 0; o < 5; ++o) acc[o] = fmaf(hv, Wfca[k * 5 + o], acc[o]);
        }
        #pragma unroll
        for (int o = 0; o < 5; ++o)
            #pragma unroll
            for (int s = 32; s > 0; s >>= 1) acc[o] += __shfl_xor(acc[o], s);
        if (lane == 0) {
            float ms = 0.f;
            #pragma unroll
            for (int o = 0; o < 5; ++o) {
                float v = acc[o] + bfca[o];
                out_atom[grow * 5 + o] = v;
                float d = v - x[grow * Dd + 5 + o];
                ms += d * d;
            }
            msum += (double)ms;
        }
    }
    if (lane == 0) sred[wid] = msum;
    __syncthreads();
    if (tid == 0) atomicAdd(acc_mse, sred[0] + sred[1] + sred[2] + sred[3]);
}

// ========== BCE over out_adj (row-structured, abits bitmask, fast math) ==========
// 1024 blocks x 32 rows; thread t handles cols t and t+256 of each row.
__global__ __launch_bounds__(256) void bce2_kernel(const float* __restrict__ out_adj,
                                                   const ushort* __restrict__ abits,
                                                   const int* __restrict__ nmask,
                                                   double* __restrict__ acc_bce) {
    __shared__ int smn[32];
    __shared__ float sred[4];
    int tid = threadIdx.x;
    int rowbase = blockIdx.x * 32;
    int gb = rowbase >> 9;                      // 32 | 512 -> constant per block
    if (tid < 32) smn[tid] = nmask[rowbase + tid];
    int j0 = tid, j1 = tid + 256;
    int cm0 = nmask[gb * 512 + j0];
    int cm1 = nmask[gb * 512 + j1];
    __syncthreads();
    int l15 = tid & 15;
    float bsum = 0.f;
    for (int r = 0; r < 32; ++r) {
        size_t grow = (size_t)(rowbase + r);
        int n = (int)(grow & 511);
        int mn = smn[r];
        const float* lrow = out_adj + grow * 512;
        const ushort* wrow = abits + grow * 32;
        float l0 = lrow[j0];
        float l1 = lrow[j1];
        int b0 = (wrow[j0 >> 4] >> l15) & 1;
        int b1 = (wrow[j1 >> 4] >> l15) & 1;
        bool ab0 = (mn != 0) && (cm0 != 0) && ((j0 == n) || b0);
        bool ab1 = (mn != 0) && (cm1 != 0) && ((j1 == n) || b1);
        bsum += fmaxf(l0, 0.f) - (ab0 ? l0 : 0.f) + __logf(1.f + __expf(-fabsf(l0)));
        bsum += fmaxf(l1, 0.f) - (ab1 ? l1 : 0.f) + __logf(1.f + __expf(-fabsf(l1)));
    }
    #pragma unroll
    for (int o = 32; o > 0; o >>= 1) bsum += __shfl_xor(bsum, o);
    if ((tid & 63) == 0) sred[tid >> 6] = bsum;
    __syncthreads();
    if (tid == 0) atomicAdd(acc_bce, (double)(sred[0] + sred[1] + sred[2] + sred[3]));
}

// ======== FALLBACK (small ws): R5 fp32 conv + fused adj/BCE ========
__global__ __launch_bounds__(256) void convgemm_kernel(const float* __restrict__ X,
                                                       const float* __restrict__ Wc,
                                                       const float* __restrict__ bias,
                                                       float* __restrict__ Y,
                                                       int Cin, int Tin, int Cout) {
    __shared__ float As[16][68];
    __shared__ float Bs[16][68];
    int K = Cin * 2, Tout = Tin - 1;
    int tid = threadIdx.x, bz = blockIdx.z;
    const float* Xb = X + (size_t)bz * Cin * Tin;
    int m0 = blockIdx.y << 6, col0 = blockIdx.x << 6;
    int tx = tid & 15, ty = tid >> 4;
    float acc[4][4] = {};
    int sm = tid & 63, sks = (tid >> 6) << 2;
    int bkk = tid >> 4, btof = (tid & 15) << 2;
    for (int k0 = 0; k0 < K; k0 += 16) {
        float4 av = *(const float4*)&Wc[(size_t)(m0 + sm) * K + k0 + sks];
        As[sks + 0][sm] = av.x; As[sks + 1][sm] = av.y;
        As[sks + 2][sm] = av.z; As[sks + 3][sm] = av.w;
        {
            int kg = k0 + bkk, i = kg >> 1, par = kg & 1;
            const float* xr = Xb + (size_t)i * Tin;
            #pragma unroll
            for (int j = 0; j < 4; ++j) {
                int t = col0 + btof + j + par;
                if (t > Tin - 1) t = Tin - 1;
                Bs[bkk][btof + j] = xr[t];
            }
        }
        __syncthreads();
        #pragma unroll
        for (int kk = 0; kk < 16; ++kk) {
            float4 a4 = *(const float4*)&As[kk][ty << 2];
            float4 b4 = *(const float4*)&Bs[kk][tx << 2];
            float a[4] = {a4.x, a4.y, a4.z, a4.w};
            float bb[4] = {b4.x, b4.y, b4.z, b4.w};
            #pragma unroll
            for (int i = 0; i < 4; ++i)
                #pragma unroll
                for (int j = 0; j < 4; ++j)
                    acc[i][j] = fmaf(a[i], bb[j], acc[i][j]);
        }
        __syncthreads();
    }
    #pragma unroll
    for (int i = 0; i < 4; ++i) {
        int m = m0 + (ty << 2) + i;
        float bv = bias[m];
        #pragma unroll
        for (int j = 0; j < 4; ++j) {
            int col = col0 + (tx << 2) + j;
            if (col < Tout)
                Y[((size_t)bz * Cout + m) * Tout + col] = fmaxf(acc[i][j] + bv, 0.f);
        }
    }
}

__global__ __launch_bounds__(256) void adjbce_kernel(const float* __restrict__ c2,
                                                     const float* __restrict__ Wfcj,
                                                     const float* __restrict__ bfcj,
                                                     const float* __restrict__ adj,
                                                     const int* __restrict__ nmask,
                                                     float* __restrict__ out_adj,
                                                     double* __restrict__ acc_bce,
                                                     int b0) {
    __shared__ float cs[8][126];
    __shared__ int smn[8];
    __shared__ float sred[4];
    int tid = threadIdx.x;
    int lbase = blockIdx.x * 8;
    size_t growbase = (size_t)b0 * Nn + lbase;
    int gb = (int)(growbase >> 9);
    for (int e = tid; e < 8 * 126; e += 256) {
        int r = e / 126, k = e - r * 126;
        cs[r][k] = c2[(size_t)(lbase + r) * 126 + k];
    }
    if (tid < 8) smn[tid] = nmask[growbase + tid];
    __syncthreads();
    int j0 = tid, j1 = tid + 256;
    float l0[8], l1[8];
    float bj0 = bfcj[j0], bj1 = bfcj[j1];
    #pragma unroll
    for (int r = 0; r < 8; ++r) { l0[r] = bj0; l1[r] = bj1; }
    for (int k = 0; k < 126; ++k) {
        float w0 = Wfcj[k * Nn + j0];
        float w1 = Wfcj[k * Nn + j1];
        #pragma unroll
        for (int r = 0; r < 8; ++r) {
            float cv = cs[r][k];
            l0[r] = fmaf(cv, w0, l0[r]);
            l1[r] = fmaf(cv, w1, l1[r]);
        }
    }
    int cm0 = nmask[(size_t)(gb << 9) + j0];
    int cm1 = nmask[(size_t)(gb << 9) + j1];
    float bsum = 0.f;
    #pragma unroll
    for (int r = 0; r < 8; ++r) {
        size_t grow = growbase + r;
        int n = (int)(grow & 511);
        int mn = smn[r];
        float a0 = adj[grow * Nn + j0];
        float a1 = adj[grow * Nn + j1];
        out_adj[grow * Nn + j0] = l0[r];
        out_adj[grow * Nn + j1] = l1[r];
        bool ab0 = (mn != 0) && (cm0 != 0) && ((j0 == n) || (a0 > 0.f));
        bool ab1 = (mn != 0) && (cm1 != 0) && ((j1 == n) || (a1 > 0.f));
        bsum += fmaxf(l0[r], 0.f) - (ab0 ? l0[r] : 0.f) + log1pf(expf(-fabsf(l0[r])));
        bsum += fmaxf(l1[r], 0.f) - (ab1 ? l1[r] : 0.f) + log1pf(expf(-fabsf(l1[r])));
    }
    #pragma unroll
    for (int o = 32; o > 0; o >>= 1) bsum += __shfl_xor(bsum, o);
    if ((tid & 63) == 0) sred[tid >> 6] = bsum;
    __syncthreads();
    if (tid == 0) atomicAdd(acc_bce, (double)(sred[0] + sred[1] + sred[2] + sred[3]));
}

// ================= final loss =================
__global__ void loss_kernel(const double* __restrict__ acc, float* __restrict__ out) {
    double ce  = acc[0] / 32768.0;
    double bce = acc[1] / 16777216.0;
    double mse = acc[2] / 163840.0;
    double kl  = -0.5 * acc[3];
    double bm = (mse != 0.0) ? fabs(ce + bce) : 0.0;   // beta*mse
    out[0] = (float)(ce + bm + bce + 1e-3 * kl);
}

extern "C" void kernel_launch(void* const* d_in, const int* in_sizes, int n_in,
                              void* d_out, int out_size, void* d_ws, size_t ws_size,
                              hipStream_t stream) {
    const float* x      = (const float*)d_in[0];
    const float* adj    = (const float*)d_in[1];
    const int*   nmask  = (const int*)d_in[2];
    const float* eps    = (const float*)d_in[3];
    const float* W_rel  = (const float*)d_in[4];
    const float* b_rel  = (const float*)d_in[5];
    const float* W_root = (const float*)d_in[6];
    const float* W_mu   = (const float*)d_in[7];
    const float* b_mu   = (const float*)d_in[8];
    const float* W_lv   = (const float*)d_in[9];
    const float* b_lv   = (const float*)d_in[10];
    const float* Wx1    = (const float*)d_in[11];
    const float* bx1    = (const float*)d_in[12];
    const float* Wx2    = (const float*)d_in[13];
    const float* bx2    = (const float*)d_in[14];
    const float* Wx3    = (const float*)d_in[15];
    const float* bx3    = (const float*)d_in[16];
    const float* Wa1    = (const float*)d_in[17];
    const float* ba1    = (const float*)d_in[18];
    const float* Wa2    = (const float*)d_in[19];
    const float* ba2    = (const float*)d_in[20];
    const float* Wa3    = (const float*)d_in[21];
    const float* ba3    = (const float*)d_in[22];
    const float* Wc1    = (const float*)d_in[23];
    const float* bc1    = (const float*)d_in[24];
    const float* Wc2    = (const float*)d_in[25];
    const float* bc2    = (const float*)d_in[26];
    const float* W_fcx  = (const float*)d_in[27];
    const float* b_fcx  = (const float*)d_in[28];
    const float* W_fca  = (const float*)d_in[29];
    const float* b_fca  = (const float*)d_in[30];
    const float* W_fcj  = (const float*)d_in[31];
    const float* b_fcj  = (const float*)d_in[32];

    float* out = (float*)d_out;
    char* region = (char*)(out + OUT_ADJ);
    ushort* t1 = (ushort*)(region + T1_OFF);
    ushort* t2 = (ushort*)(region + T2_OFF);
    ushort* hx = (ushort*)(region + HX_OFF);
    float*  Zf = (float*)(region + Z_OFF);
    ushort* Zb = (ushort*)(region + Z_OFF);
    float*  axs_g = (float*)(region + AXS_OFF);

    // MLP-phase weights in region (dead before conv phase)
    ushort* wt_x1  = (ushort*)(region + WT_OFF);
    ushort* wt_x2  = wt_x1 + 65536;
    ushort* wt_x3  = wt_x2 + 262144;
    ushort* wt_a1  = wt_x3 + 131072;
    ushort* wt_a2  = wt_a1 + 65536;
    ushort* wt_a3  = wt_a2 + 262144;
    ushort* wt_mu  = wt_a3 + 131072;
    ushort* wt_lv  = wt_mu + 32768;
    ushort* wt_fcx = wt_lv + 32768;
    ushort* wt_enc = wt_fcx + 36864;       // [256][64] bf16 hi|lo combined W_rel/W_root

    // conv-phase weights + buffers in d_ws
    double* acc = (double*)d_ws;
    ushort* wc1b   = (ushort*)((char*)d_ws + 256);
    ushort* wc2b   = wc1b + 262144;
    ushort* wt_fcj = wc2b + 262144;
    // abits (2 MB) lives in d_ws so the out_adj write can't clobber it (race-safe).
    ushort* abits_ws = (ushort*)((char*)d_ws + 1179904);
    char* convbuf = (char*)d_ws + 1179904 + 2097152;
    bool fastConv = ws_size >= (size_t)1179904 + 2097152 + 196608;
    // fallback: abits unread -> park it in the region gap (clobbered later, harmless)
    ushort* abits = fastConv ? abits_ws : (ushort*)(region + ABITS_FB_OFF);

    hipMemsetAsync(d_ws, 0, 256, stream);

    // ---- prep table ----
    PTable tab;
    int t0 = 0;
    auto setT = [&](int i, const float* s, ushort* d, int R, int C, int Cp, int Kp) {
        tab.d[i] = {s, d, R, C, Cp, Kp, t0, 0};
        t0 += ((Cp + 31) / 32) * ((Kp + 31) / 32);
    };
    setT(0, Wx1, wt_x1, 128, 512, 512, 128);
    setT(1, Wx2, wt_x2, 512, 512, 512, 512);
    setT(2, Wx3, wt_x3, 512, 256, 256, 512);
    setT(3, Wa1, wt_a1, 128, 512, 512, 128);
    setT(4, Wa2, wt_a2, 512, 512, 512, 512);
    setT(5, Wa3, wt_a3, 512, 256, 256, 512);
    setT(6, W_mu, wt_mu, 256, 128, 128, 256);
    setT(7, W_lv, wt_lv, 256, 128, 128, 256);
    // encoder combined weight [256][64] hi|lo (disjoint strided writes, koff = mode-64)
    setT(8,  W_rel,  wt_enc, 10, 256, 256, 10); tab.d[8].mode  = 64 + 0;    // rel hi  k 0..9
    setT(9,  W_root, wt_enc, 10, 256, 256, 10); tab.d[9].mode  = 64 + 10;   // root hi k 10..19
    setT(10, W_rel,  wt_enc, 0,  0,   256, 12); tab.d[10].mode = 64 + 20;   // zeros   k 20..31
    setT(11, W_rel,  wt_enc, 10, 256, 256, 10); tab.d[11].mode = 64 + 32;   // rel lo  k 32..41
    setT(12, W_root, wt_enc, 10, 256, 256, 10); tab.d[12].mode = 64 + 42;   // root lo k 42..51
    setT(13, W_rel,  wt_enc, 0,  0,   256, 12); tab.d[13].mode = 64 + 52;   // zeros   k 52..63
    setT(14, W_fcx, wt_fcx, 256, 140, 144, 256);
    int t_nofcj = t0;
    setT(15, W_fcj, wt_fcj, 126, 512, 512, 128);
    tab.d[16] = {Wc1, wc1b, 262144, 0, 0, 0, t0, 1}; t0 += 32;
    tab.d[17] = {Wc2, wc2b, 262144, 0, 0, 0, t0, 1}; t0 += 32;
    prep_kernel<<<fastConv ? t0 : t_nofcj, 256, 0, stream>>>(tab);

    // ---- encoder: memory-heavy agg (+ adj>0 bitpack) + all-MFMA enc2 ----
    agg_kernel<<<ROWS / 16, 256, 0, stream>>>(adj, x, axs_g, abits);
    enc2_kernel<<<ROWS / 16, 256, 0, stream>>>(axs_g, wt_enc, b_rel, nmask,
                                               wt_mu, b_mu, wt_lv, b_lv, eps,
                                               fastConv ? (void*)Zb : (void*)Zf,
                                               fastConv ? 1 : 0, acc + 3);

    // ---- MLP chains (fastConv: Z is bf16 -> a_bf16 staging, no conversion) ----
    const void* Zin = fastConv ? (const void*)Zb : (const void*)Zf;
    int zb = fastConv ? 1 : 0;
    for (int c = 0; c < 2; ++c) {
        int r0 = c * CH;
        const void* Zc = fastConv ? (const void*)(Zb + (size_t)r0 * Ll)
                                  : (const void*)(Zf + (size_t)r0 * Ll);
        mgemm_kernel<<<dim3(4, 128), 256, 0, stream>>>(Zc, zb, wt_x1, bx1, t1, 0, 512, 128, 512, 1);
        mgemm_kernel<<<dim3(4, 128), 256, 0, stream>>>(t1, 1, wt_x2, bx2, t2, 0, 512, 512, 512, 1);
        mgemm_kernel<<<dim3(2, 128), 256, 0, stream>>>(t2, 1, wt_x3, bx3, hx, 0, 256, 512, 256, 0);
        ce_kernel<<<CH / 16, 256, 0, stream>>>(hx, wt_fcx, b_fcx, x, out + OUT_CLASS, acc + 0, r0);
    }
    for (int c = 0; c < 2; ++c) {
        int r0 = c * CH;
        const void* Zc = fastConv ? (const void*)(Zb + (size_t)r0 * Ll)
                                  : (const void*)(Zf + (size_t)r0 * Ll);
        mgemm_kernel<<<dim3(4, 128), 256, 0, stream>>>(Zc, zb, wt_a1, ba1, t1, 0, 512, 128, 512, 1);
        mgemm_kernel<<<dim3(4, 128), 256, 0, stream>>>(t1, 1, wt_a2, ba2, t2, 0, 512, 512, 512, 1);
        mgemm_kernel<<<dim3(2, 128), 256, 0, stream>>>(t2, 1, wt_a3, ba3, hx, 0, 256, 512, 256, 0);
        atom_kernel<<<CH / 64, 256, 0, stream>>>(hx, W_fca, b_fca, x, out + OUT_ATOM, acc + 2, r0);
    }

    // ---- conv path + adj head + dedicated BCE pass (abits-based) ----
    if (fastConv) {
        size_t avail = ws_size - 1179904 - 2097152;
        int NB = 64;
        while (NB > 1 && (size_t)NB * 196608 > avail) NB >>= 1;
        ushort* c1 = (ushort*)convbuf;
        ushort* c2 = c1 + (size_t)NB * 32768;
        for (int b0 = 0; b0 < 64; b0 += NB) {
            convmfma_kernel<<<dim3(1, 2, NB), 256, 0, stream>>>(Zb + (size_t)b0 * 65536, 1, 65536,
                                                               wc1b, bc1, c1, 256, 1024, 127);
            convmfma_kernel<<<dim3(1, 4, NB), 256, 0, stream>>>(c1, 1, 32768,
                                                               wc2b, bc2, c2, 512, 512, 126);
            mgemm_kernel<<<dim3(4, NB * 4), 256, 0, stream>>>(c2, 1, wt_fcj, b_fcj,
                                                              out + OUT_ADJ + (size_t)b0 * 262144, 1,
                                                              512, 128, 512, 0);
        }
        bce2_kernel<<<1024, 256, 0, stream>>>(out + OUT_ADJ, abits, nmask, acc + 1);
    } else {
        size_t avail = (ws_size > 256) ? ws_size - 256 : 0;
        int NB = 64;
        while (NB > 1 && (size_t)NB * 388096 > avail) NB >>= 1;
        float* c1 = (float*)((char*)d_ws + 256);
        float* c2 = (float*)((char*)d_ws + 256 + (size_t)NB * 256 * 127 * 4);
        for (int b0 = 0; b0 < 64; b0 += NB) {
            convgemm_kernel<<<dim3(2, 4, NB), 256, 0, stream>>>(Zf + (size_t)b0 * 65536, Wc1, bc1, c1, 512, 128, 256);
            convgemm_kernel<<<dim3(2, 8, NB), 256, 0, stream>>>(c1, Wc2, bc2, c2, 256, 127, 512);
            adjbce_kernel<<<NB * Nn / 8, 256, 0, stream>>>(c2, W_fcj, b_fcj, adj, nmask,
                                                           out + OUT_ADJ, acc + 1, b0);
        }
    }

    loss_kernel<<<1, 1, 0, stream>>>(acc, out);
}

// Round 16
// 741.930 us; speedup vs baseline: 1.0308x; 1.0069x over previous
//
#include <hip/hip_runtime.h>
#include <hip/hip_bf16.h>
#include <cstdint>

using bf16x8 = __attribute__((ext_vector_type(8))) __bf16;
using floatx4 = __attribute__((ext_vector_type(4))) float;
typedef unsigned short ushort;

#define Nn  512
#define Dd  10
#define Hh  256
#define Ll  128
#define CLS 140
#define ROWS 32768
#define CH  16384

// out buffer (fp32) element offsets
#define OUT_CLASS 1ull
#define OUT_ATOM  4587521ull
#define OUT_ADJ   4751361ull

// byte offsets inside dead out_adj region (67,108,864 B, base ≡ 4 mod 16)
#define T1_OFF 12ull
#define T2_OFF (12ull + 16777216ull)
#define HX_OFF (12ull + 33554432ull)
#define WT_OFF 41943068ull          // region+WT_OFF ≡ 0 mod 16
#define AXS_OFF 45088780ull         // region+AXS_OFF ≡ 0 mod 16
#define ABITS_FB_OFF 47710224ull    // fallback-only abits (unused there; clobber-safe)
#define Z_OFF  50331644ull          // region+Z_OFF ≡ 0 mod 16

static __device__ __forceinline__ ushort bfb(float v) {
    __hip_bfloat16 h = __float2bfloat16(v);
    return *reinterpret_cast<ushort*>(&h);
}
static __device__ __forceinline__ float fbf(ushort u) {
    __hip_bfloat16 h = *reinterpret_cast<__hip_bfloat16*>(&u);
    return __bfloat162float(h);
}
static __device__ __forceinline__ unsigned pk2(float a, float b) {
    return (unsigned)bfb(a) | ((unsigned)bfb(b) << 16);
}

// ================= prep: weight convert/transpose to bf16 =================
// mode 0: transpose convert dst[n*Kp+k]
// mode 1: plain convert
// mode >= 64: strided write into [Cp][64] hi|lo layout: dst[n*64 + (mode-64) + k];
//             (mode-64) >= 32 -> store lo part: bf16(v - fbf(bf16(v)))
struct PDesc { const float* src; ushort* dst; int srcR, srcC, Cp, Kp, tile0, mode; };
struct PTable { PDesc d[18]; };

__global__ __launch_bounds__(256) void prep_kernel(PTable tab) {
    __shared__ float tile[32][33];
    int bt = blockIdx.x, tid = threadIdx.x;
    int di = 0;
    #pragma unroll
    for (int i = 1; i < 18; ++i) if (bt >= tab.d[i].tile0) di = i;
    PDesc d = tab.d[di];
    int lt = bt - d.tile0;
    if (d.mode == 1) {  // plain convert
        long base = (long)lt * 8192;
        const float* s = d.src;
        ushort* o = d.dst;
        for (int i = tid; i < 2048; i += 256) {
            long idx = base + (long)i * 4;
            float4 v = *(const float4*)&s[idx];
            unsigned u0 = pk2(v.x, v.y), u1 = pk2(v.z, v.w);
            *(uint2*)&o[idx] = (uint2){u0, u1};
        }
        return;
    }
    int tilesK = (d.Kp + 31) >> 5;
    int k0 = (lt % tilesK) << 5, n0 = (lt / tilesK) << 5;
    int tx = tid & 31, ty = tid >> 5;
    for (int ky = ty; ky < 32; ky += 8) {
        int k = k0 + ky, n = n0 + tx;
        float v = (k < d.srcR && n < d.srcC) ? d.src[(size_t)k * d.srcC + n] : 0.f;
        tile[ky][tx] = v;
    }
    __syncthreads();
    for (int ny = ty; ny < 32; ny += 8) {
        int n = n0 + ny, k = k0 + tx;
        if (n < d.Cp && k < d.Kp) {
            float v = tile[tx][ny];
            if (d.mode >= 64) {
                int koff = d.mode - 64;
                ushort u;
                if (koff >= 32) u = bfb(v - fbf(bfb(v)));   // lo residual
                else u = bfb(v);                            // hi
                d.dst[(size_t)n * 64 + koff + k] = u;
            } else {
                d.dst[(size_t)n * d.Kp + k] = bfb(v);
            }
        }
    }
}

// ================= encoder stage 1: adj aggregation + adj>0 bitpack =================
// float4 adj loads (16B/lane), all 8 hoisted into registers before processing so
// the HBM latencies overlap (launch_bounds(256,6): LDS already limits to 6
// blocks/CU, so allow ~85 VGPRs instead of strangling the allocator at 64).
__global__ __launch_bounds__(256, 6) void agg_kernel(
    const float* __restrict__ adj, const float* __restrict__ x,
    float* __restrict__ axs_g, ushort* __restrict__ abits)
{
    __shared__ float4 xs4[1536];            // 512 rows x 12 floats (padded)
    float* xs = (float*)xs4;
    int tid = threadIdx.x;
    int rowbase = blockIdx.x * 16;
    int b = rowbase >> 9, rowloc = rowbase & 511;
    const float* xb = x + (size_t)b * 5120;
    for (int e = tid; e < 6144; e += 256) {
        int j = e / 12, d = e - j * 12;
        xs[e] = (d < 10) ? xb[j * 10 + d] : 0.f;
    }
    __syncthreads();
    int g = tid >> 4, l16 = tid & 15;
    int row = rowbase + g;
    const float4* arow4 = (const float4*)(adj + (size_t)row * Nn);
    float accv[10] = {};
    float deg = 0.f;
    float4 av[8];
    #pragma unroll
    for (int it = 0; it < 8; ++it) av[it] = arow4[l16 + (it << 4)];
    #define ACCUM(a_, j_) do { float a = (a_); if (a != 0.f) {               \
        const float4 v0 = xs4[(j_) * 3 + 0];                                 \
        const float4 v1 = xs4[(j_) * 3 + 1];                                 \
        const float4 v2 = xs4[(j_) * 3 + 2];                                 \
        deg += a;                                                            \
        accv[0] += a * v0.x; accv[1] += a * v0.y;                            \
        accv[2] += a * v0.z; accv[3] += a * v0.w;                            \
        accv[4] += a * v1.x; accv[5] += a * v1.y;                            \
        accv[6] += a * v1.z; accv[7] += a * v1.w;                            \
        accv[8] += a * v2.x; accv[9] += a * v2.y; } } while (0)
    #pragma unroll
    for (int it = 0; it < 8; ++it) {
        int nib = ((av[it].x > 0.f) ? 1 : 0) | ((av[it].y > 0.f) ? 2 : 0) |
                  ((av[it].z > 0.f) ? 4 : 0) | ((av[it].w > 0.f) ? 8 : 0);
        int n2 = nib | (__shfl_xor(nib, 1) << 4);
        int n4 = n2 | (__shfl_xor(n2, 2) << 8);
        if ((l16 & 3) == 0) abits[(size_t)row * 32 + it * 4 + (l16 >> 2)] = (ushort)n4;
        int jb = 4 * l16 + (it << 6);
        ACCUM(av[it].x, jb + 0);
        ACCUM(av[it].y, jb + 1);
        ACCUM(av[it].z, jb + 2);
        ACCUM(av[it].w, jb + 3);
    }
    #undef ACCUM
    #pragma unroll
    for (int o = 8; o > 0; o >>= 1) {
        deg += __shfl_xor(deg, o);
        #pragma unroll
        for (int d = 0; d < 10; ++d) accv[d] += __shfl_xor(accv[d], o);
    }
    float* orow = axs_g + (size_t)row * 20;
    if (l16 == 0) {
        float dg = fmaxf(deg, 1.f);
        #pragma unroll
        for (int d = 0; d < 10; ++d) orow[d] = accv[d] / dg;
    }
    if (l16 < 10) orow[10 + l16] = xs[(rowloc + g) * 12 + l16];
}

// ================= encoder stage 2: all-MFMA h -> mu/lv -> z + KL =================
// (r10 structure) Phase 3 stores mu/lv to LDS; phase 4 does z + KL coalesced.
// zbf16 != 0: write Z as bf16 (same __float2bfloat16 bits all consumers produced
// internally before -> bit-identical downstream, half the write traffic).
__global__ __launch_bounds__(256, 4) void enc2_kernel(
    const float* __restrict__ axs_g,
    const ushort* __restrict__ Wenc,       // [256][64] bf16: k<10 rel-hi, 10..19 root-hi, 32..41 rel-lo, 42..51 root-lo, rest 0
    const float* __restrict__ brel, const int* __restrict__ nmask,
    const ushort* __restrict__ Wtmu, const float* __restrict__ bmu,
    const ushort* __restrict__ Wtlv, const float* __restrict__ blv,
    const float* __restrict__ eps, void* __restrict__ Zout, int zbf16,
    double* __restrict__ acc_kl)
{
    __shared__ float sml[4096];             // [2][16][128] mu/lv (16 KB)
    __shared__ uint4 axsbRaw[160];          // 16 x 80 ushorts (hi at d<20, lo at 40..59)
    __shared__ uint4 hsbRaw[528];           // 16 x 264 ushorts
    __shared__ int smask[16];
    __shared__ float skred[4];
    ushort* axsb = (ushort*)axsbRaw;
    ushort* hsb = (ushort*)hsbRaw;
    int tid = threadIdx.x;
    int rowbase = blockIdx.x * 16;
    size_t abase = (size_t)rowbase * 20;

    // phase A: stage axs as split-bf16 A fragments
    for (int e = tid; e < 1280; e += 256) {
        int r = e / 80, d = e - r * 80;
        ushort u = 0;
        if (d < 20) {
            u = bfb(axs_g[abase + r * 20 + d]);
        } else if (d >= 40 && d < 60) {
            float v = axs_g[abase + r * 20 + d - 40];
            u = bfb(v - fbf(bfb(v)));
        }
        axsb[e] = u;
    }
    if (tid < 16) smask[tid] = nmask[rowbase + tid];
    __syncthreads();

    int lane = tid & 63, wid = tid >> 6;
    int l15 = lane & 15, quad = lane >> 4;

    // phase 2: h via MFMA (M=16, N=256, K=32), split hi/lo for fp32 accuracy
    {
        bf16x8 ah = __builtin_bit_cast(bf16x8, *(const uint4*)(axsb + l15 * 80 + quad * 8));
        bf16x8 al = __builtin_bit_cast(bf16x8, *(const uint4*)(axsb + l15 * 80 + 40 + quad * 8));
        #pragma unroll
        for (int i = 0; i < 4; ++i) {
            int ct = wid * 4 + i;
            int col = ct * 16 + l15;
            bf16x8 bh = __builtin_bit_cast(bf16x8, *(const uint4*)(Wenc + (size_t)col * 64 + quad * 8));
            bf16x8 blo = __builtin_bit_cast(bf16x8, *(const uint4*)(Wenc + (size_t)col * 64 + 32 + quad * 8));
            floatx4 a = (floatx4){0.f, 0.f, 0.f, 0.f};
            a = __builtin_amdgcn_mfma_f32_16x16x32_bf16(al, bh, a, 0, 0, 0);
            a = __builtin_amdgcn_mfma_f32_16x16x32_bf16(ah, blo, a, 0, 0, 0);
            a = __builtin_amdgcn_mfma_f32_16x16x32_bf16(ah, bh, a, 0, 0, 0);
            float bb = brel[col];
            #pragma unroll
            for (int r4 = 0; r4 < 4; ++r4) {
                int row = quad * 4 + r4;
                float v = a[r4] + bb;
                v = (smask[row] != 0) ? fmaxf(v, 0.f) : 0.f;
                hsb[row * 264 + col] = bfb(v);
            }
        }
    }
    __syncthreads();

    // phase 3: mu/lv MFMA -> sml (fp32, bit-preserving)
    #pragma unroll
    for (int i = 0; i < 2; ++i) {
        int ct = wid * 2 + i;
        int col = ct * 16 + l15;
        floatx4 amu = (floatx4){0.f, 0.f, 0.f, 0.f};
        floatx4 alv = (floatx4){0.f, 0.f, 0.f, 0.f};
        #pragma unroll
        for (int k0 = 0; k0 < 8; ++k0) {
            bf16x8 af = __builtin_bit_cast(bf16x8, *(const uint4*)(hsb + l15 * 264 + k0 * 32 + quad * 8));
            bf16x8 bm = __builtin_bit_cast(bf16x8, *(const uint4*)(Wtmu + (size_t)col * 256 + k0 * 32 + quad * 8));
            bf16x8 bl = __builtin_bit_cast(bf16x8, *(const uint4*)(Wtlv + (size_t)col * 256 + k0 * 32 + quad * 8));
            amu = __builtin_amdgcn_mfma_f32_16x16x32_bf16(af, bm, amu, 0, 0, 0);
            alv = __builtin_amdgcn_mfma_f32_16x16x32_bf16(af, bl, alv, 0, 0, 0);
        }
        float bmv = bmu[col], blv_ = blv[col];
        #pragma unroll
        for (int r4 = 0; r4 < 4; ++r4) {
            int row = quad * 4 + r4;
            sml[row * 128 + col] = amu[r4] + bmv;
            sml[2048 + row * 128 + col] = alv[r4] + blv_;
        }
    }
    __syncthreads();

    // phase 4: z + KL, fully coalesced (thread t -> f4 idx t and t+256)
    {
        float kt = 0.f;
        const float4* ep4 = (const float4*)(eps + (size_t)rowbase * Ll);
        const float4* mu4 = (const float4*)sml;
        const float4* lv4 = (const float4*)(sml + 2048);
        #pragma unroll
        for (int i = 0; i < 2; ++i) {
            int e4 = tid + i * 256;
            float4 ee = ep4[e4];
            float4 mu = mu4[e4];
            float4 lv = lv4[e4];
            float4 zz;
            zz.x = mu.x + ee.x * expf(0.5f * lv.x);
            zz.y = mu.y + ee.y * expf(0.5f * lv.y);
            zz.z = mu.z + ee.z * expf(0.5f * lv.z);
            zz.w = mu.w + ee.w * expf(0.5f * lv.w);
            if (zbf16) {
                ushort* Zb = (ushort*)Zout + (size_t)rowbase * Ll;
                *(uint2*)(Zb + e4 * 4) = (uint2){pk2(zz.x, zz.y), pk2(zz.z, zz.w)};
            } else {
                float4* z4 = (float4*)Zout + (size_t)rowbase * (Ll / 4);
                z4[e4] = zz;
            }
            kt += 1.f + lv.x - mu.x * mu.x - expf(lv.x);
            kt += 1.f + lv.y - mu.y * mu.y - expf(lv.y);
            kt += 1.f + lv.z - mu.z * mu.z - expf(lv.z);
            kt += 1.f + lv.w - mu.w * mu.w - expf(lv.w);
        }
        #pragma unroll
        for (int o = 32; o > 0; o >>= 1) kt += __shfl_xor(kt, o);
        if (lane == 0) skred[wid] = kt;
    }
    __syncthreads();
    if (tid == 0) atomicAdd(acc_kl, (double)(skred[0] + skred[1] + skred[2] + skred[3]));
}

// ================= unified MFMA GEMM: C = relu?(A @ Bt^T + bias) =================
// A row-major [M][K] fp32 or bf16; Bt bf16 [N][K]; C bf16 or fp32, row stride ldc.
// XCD-aware block swizzle (bijective, requires gridDim.x*gridDim.y % 8 == 0).
__global__ __launch_bounds__(256) void mgemm_kernel(const void* __restrict__ A, int a_bf16,
                                                    const ushort* __restrict__ Bt,
                                                    const float* __restrict__ bias,
                                                    void* __restrict__ Cp, int c_fp32,
                                                    int N, int K, int ldc, int relu) {
    __shared__ uint4 AsRaw[640];
    __shared__ uint4 BsRaw[640];
    ushort* As = (ushort*)AsRaw;
    ushort* Bs = (ushort*)BsRaw;
    int tid = threadIdx.x;
    int nwg = gridDim.x * gridDim.y;
    int bid = blockIdx.y * gridDim.x + blockIdx.x;
    int swz = (bid & 7) * (nwg >> 3) + (bid >> 3);
    int row0 = (swz / gridDim.x) << 7, col0 = (swz % gridDim.x) << 7;
    int lane = tid & 63, wid = tid >> 6;
    int wm = (wid >> 1) * 64, wn = (wid & 1) * 64;
    int l15 = lane & 15, quad = lane >> 4;
    floatx4 acc[4][4];
    #pragma unroll
    for (int i = 0; i < 4; ++i)
        #pragma unroll
        for (int j = 0; j < 4; ++j) acc[i][j] = (floatx4){0.f, 0.f, 0.f, 0.f};
    int am = tid & 127, aseg = tid >> 7;
    for (int k0 = 0; k0 < K; k0 += 32) {
        {
            uint4* dst = (uint4*)(As + am * 40 + aseg * 16);
            if (a_bf16) {
                const uint4* ap = (const uint4*)((const ushort*)A + (size_t)(row0 + am) * K + k0 + aseg * 16);
                dst[0] = ap[0]; dst[1] = ap[1];
            } else {
                const float4* ap = (const float4*)((const float*)A + (size_t)(row0 + am) * K + k0 + aseg * 16);
                float4 f0 = ap[0], f1 = ap[1], f2 = ap[2], f3 = ap[3];
                dst[0] = (uint4){pk2(f0.x, f0.y), pk2(f0.z, f0.w), pk2(f1.x, f1.y), pk2(f1.z, f1.w)};
                dst[1] = (uint4){pk2(f2.x, f2.y), pk2(f2.z, f2.w), pk2(f3.x, f3.y), pk2(f3.z, f3.w)};
            }
        }
        {
            const uint4* bp = (const uint4*)(Bt + (size_t)(col0 + am) * K + k0 + aseg * 16);
            uint4* dst = (uint4*)(Bs + am * 40 + aseg * 16);
            dst[0] = bp[0]; dst[1] = bp[1];
        }
        __syncthreads();
        bf16x8 af[4], bfv[4];
        #pragma unroll
        for (int mt = 0; mt < 4; ++mt)
            af[mt] = __builtin_bit_cast(bf16x8, *(const uint4*)(As + (wm + mt * 16 + l15) * 40 + quad * 8));
        #pragma unroll
        for (int nt = 0; nt < 4; ++nt)
            bfv[nt] = __builtin_bit_cast(bf16x8, *(const uint4*)(Bs + (wn + nt * 16 + l15) * 40 + quad * 8));
        #pragma unroll
        for (int mt = 0; mt < 4; ++mt)
            #pragma unroll
            for (int nt = 0; nt < 4; ++nt)
                acc[mt][nt] = __builtin_amdgcn_mfma_f32_16x16x32_bf16(af[mt], bfv[nt], acc[mt][nt], 0, 0, 0);
        __syncthreads();
    }
    // epilogue: mt,r outer / nt inner (adjacent store chunks per row -> better combining)
    float bvv[4];
    int ncols[4];
    #pragma unroll
    for (int nt = 0; nt < 4; ++nt) {
        ncols[nt] = col0 + wn + nt * 16 + l15;
        bvv[nt] = bias[ncols[nt]];
    }
    #pragma unroll
    for (int mt = 0; mt < 4; ++mt)
        #pragma unroll
        for (int r = 0; r < 4; ++r) {
            size_t m = row0 + wm + mt * 16 + quad * 4 + r;
            #pragma unroll
            for (int nt = 0; nt < 4; ++nt) {
                int n = ncols[nt];
                float v = acc[mt][nt][r] + bvv[nt];
                if (relu) v = fmaxf(v, 0.f);
                if (c_fp32) ((float*)Cp)[m * ldc + n] = v;
                else ((ushort*)Cp)[m * ldc + n] = bfb(v);
            }
        }
}

// ================= conv (K=2, VALID, relu) as MFMA GEMM =================
__global__ __launch_bounds__(256) void convmfma_kernel(const void* __restrict__ X, int x_bf16,
                                                       long xBS,
                                                       const ushort* __restrict__ Ab,
                                                       const float* __restrict__ bias,
                                                       ushort* __restrict__ Y,
                                                       int Cout, int K, int Tout) {
    __shared__ uint4 AsRaw[640];
    __shared__ uint4 BsRaw[640];
    ushort* As = (ushort*)AsRaw;
    ushort* Bs = (ushort*)BsRaw;
    int tid = threadIdx.x, bz = blockIdx.z;
    int row0 = blockIdx.y << 7;
    int lane = tid & 63, wid = tid >> 6;
    int wm = (wid >> 1) * 64, wn = (wid & 1) * 64;
    int l15 = lane & 15, quad = lane >> 4;
    floatx4 acc[4][4];
    #pragma unroll
    for (int i = 0; i < 4; ++i)
        #pragma unroll
        for (int j = 0; j < 4; ++j) acc[i][j] = (floatx4){0.f, 0.f, 0.f, 0.f};
    int am = tid & 127, aseg = tid >> 7;
    int tnext = (am + 1 > 127) ? 127 : am + 1;
    for (int k0 = 0; k0 < K; k0 += 32) {
        {
            const uint4* ap = (const uint4*)(Ab + (size_t)(row0 + am) * K + k0 + aseg * 16);
            uint4* dst = (uint4*)(As + am * 40 + aseg * 16);
            dst[0] = ap[0]; dst[1] = ap[1];
        }
        {
            unsigned r[8];
            if (x_bf16) {
                const ushort* Xb = (const ushort*)X + (size_t)bz * xBS;
                #pragma unroll
                for (int q = 0; q < 8; ++q) {
                    int kk = k0 + aseg * 16 + 2 * q, i = kk >> 1;
                    r[q] = (unsigned)Xb[i * 128 + am] | ((unsigned)Xb[i * 128 + tnext] << 16);
                }
            } else {
                const float* Xf = (const float*)X + (size_t)bz * xBS;
                #pragma unroll
                for (int q = 0; q < 8; ++q) {
                    int kk = k0 + aseg * 16 + 2 * q, i = kk >> 1;
                    r[q] = pk2(Xf[i * 128 + am], Xf[i * 128 + tnext]);
                }
            }
            uint4* dst = (uint4*)(Bs + am * 40 + aseg * 16);
            dst[0] = (uint4){r[0], r[1], r[2], r[3]};
            dst[1] = (uint4){r[4], r[5], r[6], r[7]};
        }
        __syncthreads();
        bf16x8 af[4], bfv[4];
        #pragma unroll
        for (int mt = 0; mt < 4; ++mt)
            af[mt] = __builtin_bit_cast(bf16x8, *(const uint4*)(As + (wm + mt * 16 + l15) * 40 + quad * 8));
        #pragma unroll
        for (int nt = 0; nt < 4; ++nt)
            bfv[nt] = __builtin_bit_cast(bf16x8, *(const uint4*)(Bs + (wn + nt * 16 + l15) * 40 + quad * 8));
        #pragma unroll
        for (int mt = 0; mt < 4; ++mt)
            #pragma unroll
            for (int nt = 0; nt < 4; ++nt)
                acc[mt][nt] = __builtin_amdgcn_mfma_f32_16x16x32_bf16(af[mt], bfv[nt], acc[mt][nt], 0, 0, 0);
        __syncthreads();
    }
    #pragma unroll
    for (int mt = 0; mt < 4; ++mt)
        #pragma unroll
        for (int r = 0; r < 4; ++r) {
            int m = row0 + wm + mt * 16 + quad * 4 + r;
            float bv = bias[m];
            #pragma unroll
            for (int nt = 0; nt < 4; ++nt) {
                int col = wn + nt * 16 + l15;
                float v = fmaxf(acc[mt][nt][r] + bv, 0.f);
                if (col >= Tout) v = 0.f;
                Y[((size_t)bz * Cout + m) * 128 + col] = bfb(v);
            }
        }
}

// ================= class head + CE (MFMA, 16 rows/block) =================
__global__ __launch_bounds__(256) void ce_kernel(const ushort* __restrict__ hx,
                                                 const ushort* __restrict__ Wt,
                                                 const float* __restrict__ bfcx,
                                                 const float* __restrict__ x,
                                                 float* __restrict__ out_class,
                                                 double* __restrict__ acc_ce,
                                                 int row0) {
    __shared__ ushort hxb[16 * 264];
    __shared__ float slog[16][144];
    __shared__ float sce[16];
    int tid = threadIdx.x;
    int lbase = blockIdx.x * 16;
    for (int e = tid; e < 512; e += 256) {
        int r = e >> 5, seg = e & 31;
        *(uint4*)(hxb + r * 264 + seg * 8) = *(const uint4*)(hx + (size_t)(lbase + r) * 256 + seg * 8);
    }
    __syncthreads();
    int lane = tid & 63, wid = tid >> 6, l15 = lane & 15, quad = lane >> 4;
    for (int ct = wid; ct < 9; ct += 4) {
        floatx4 a = (floatx4){0.f, 0.f, 0.f, 0.f};
        #pragma unroll
        for (int k0 = 0; k0 < 8; ++k0) {
            bf16x8 af = __builtin_bit_cast(bf16x8, *(const uint4*)(hxb + l15 * 264 + k0 * 32 + quad * 8));
            bf16x8 bfr = __builtin_bit_cast(bf16x8, *(const uint4*)(Wt + (size_t)(ct * 16 + l15) * 256 + k0 * 32 + quad * 8));
            a = __builtin_amdgcn_mfma_f32_16x16x32_bf16(af, bfr, a, 0, 0, 0);
        }
        int col = ct * 16 + l15;
        float bv = (col < CLS) ? bfcx[col] : 0.f;
        #pragma unroll
        for (int r4 = 0; r4 < 4; ++r4) {
            int r = quad * 4 + r4;
            float v = a[r4] + bv;
            slog[r][col] = v;
            if (col < CLS) out_class[(size_t)(row0 + lbase + r) * CLS + col] = v;
        }
    }
    __syncthreads();
    #pragma unroll
    for (int rr = 0; rr < 4; ++rr) {
        int r = wid * 4 + rr;
        float m = -1e30f;
        for (int j = lane; j < CLS; j += 64) m = fmaxf(m, slog[r][j]);
        #pragma unroll
        for (int o = 32; o > 0; o >>= 1) m = fmaxf(m, __shfl_xor(m, o));
        float s = 0.f;
        for (int j = lane; j < CLS; j += 64) s += expf(slog[r][j] - m);
        #pragma unroll
        for (int o = 32; o > 0; o >>= 1) s += __shfl_xor(s, o);
        if (lane == 0) {
            size_t grow = (size_t)row0 + lbase + r;
            float aa = x[grow * Dd + 0];
            float ss = x[grow * Dd + 1];
            int mapping = (int)((ss - 1.f) * 20.f + (aa - 1.f));
            int idx = mapping > 0 ? mapping : 0;
            float ce = -(slog[r][idx] - m - logf(s));
            sce[r] = (mapping < 0) ? 0.f : ce;
        }
    }
    __syncthreads();
    if (tid == 0) {
        float t = 0.f;
        #pragma unroll
        for (int r = 0; r < 16; ++r) t += sce[r];
        atomicAdd(acc_ce, (double)t);
    }
}

// ================= atom head + MSE (64 rows/block, 1 atomic/block) =================
__global__ __launch_bounds__(256) void atom_kernel(const ushort* __restrict__ ha,
                                                   const float* __restrict__ Wfca,
                                                   const float* __restrict__ bfca,
                                                   const float* __restrict__ x,
                                                   float* __restrict__ out_atom,
                                                   double* __restrict__ acc_mse,
                                                   int row0) {
    __shared__ double sred[4];
    int tid = threadIdx.x;
    int wid = tid >> 6, lane = tid & 63;
    int rowblk = blockIdx.x * 64;
    double msum = 0.0;
    for (int rr = 0; rr < 16; ++rr) {
        int lrow = rowblk + wid * 16 + rr;
        size_t grow = (size_t)row0 + lrow;
        float acc[5] = {};
        for (int k = lane; k < 256; k += 64) {
            float hv = fbf(ha[(size_t)lrow * Hh + k]);
            #pragma unroll
            for (int o = 0; o < 5; ++o) acc[o] = fmaf(hv, Wfca[k * 5 + o], acc[o]);
        }
        #pragma unroll
        for (int o = 0; o < 5; ++o)
            #pragma unroll
            for (int s = 32; s > 0; s >>= 1) acc[o] += __shfl_xor(acc[o], s);
        if (lane == 0) {
            float ms = 0.f;
            #pragma unroll
            for (int o = 0; o < 5; ++o) {
                float v = acc[o] + bfca[o];
                out_atom[grow * 5 + o] = v;
                float d = v - x[grow * Dd + 5 + o];
                ms += d * d;
            }
            msum += (double)ms;
        }
    }
    if (lane == 0) sred[wid] = msum;
    __syncthreads();
    if (tid == 0) atomicAdd(acc_mse, sred[0] + sred[1] + sred[2] + sred[3]);
}

// ========== BCE over out_adj (row-structured, abits bitmask, fast math) ==========
// 1024 blocks x 32 rows; thread t handles cols t and t+256 of each row.
__global__ __launch_bounds__(256) void bce2_kernel(const float* __restrict__ out_adj,
                                                   const ushort* __restrict__ abits,
                                                   const int* __restrict__ nmask,
                                                   double* __restrict__ acc_bce) {
    __shared__ int smn[32];
    __shared__ float sred[4];
    int tid = threadIdx.x;
    int rowbase = blockIdx.x * 32;
    int gb = rowbase >> 9;                      // 32 | 512 -> constant per block
    if (tid < 32) smn[tid] = nmask[rowbase + tid];
    int j0 = tid, j1 = tid + 256;
    int cm0 = nmask[gb * 512 + j0];
    int cm1 = nmask[gb * 512 + j1];
    __syncthreads();
    int l15 = tid & 15;
    float bsum = 0.f;
    for (int r = 0; r < 32; ++r) {
        size_t grow = (size_t)(rowbase + r);
        int n = (int)(grow & 511);
        int mn = smn[r];
        const float* lrow = out_adj + grow * 512;
        const ushort* wrow = abits + grow * 32;
        float l0 = lrow[j0];
        float l1 = lrow[j1];
        int b0 = (wrow[j0 >> 4] >> l15) & 1;
        int b1 = (wrow[j1 >> 4] >> l15) & 1;
        bool ab0 = (mn != 0) && (cm0 != 0) && ((j0 == n) || b0);
        bool ab1 = (mn != 0) && (cm1 != 0) && ((j1 == n) || b1);
        bsum += fmaxf(l0, 0.f) - (ab0 ? l0 : 0.f) + __logf(1.f + __expf(-fabsf(l0)));
        bsum += fmaxf(l1, 0.f) - (ab1 ? l1 : 0.f) + __logf(1.f + __expf(-fabsf(l1)));
    }
    #pragma unroll
    for (int o = 32; o > 0; o >>= 1) bsum += __shfl_xor(bsum, o);
    if ((tid & 63) == 0) sred[tid >> 6] = bsum;
    __syncthreads();
    if (tid == 0) atomicAdd(acc_bce, (double)(sred[0] + sred[1] + sred[2] + sred[3]));
}

// ======== FALLBACK (small ws): R5 fp32 conv + fused adj/BCE ========
__global__ __launch_bounds__(256) void convgemm_kernel(const float* __restrict__ X,
                                                       const float* __restrict__ Wc,
                                                       const float* __restrict__ bias,
                                                       float* __restrict__ Y,
                                                       int Cin, int Tin, int Cout) {
    __shared__ float As[16][68];
    __shared__ float Bs[16][68];
    int K = Cin * 2, Tout = Tin - 1;
    int tid = threadIdx.x, bz = blockIdx.z;
    const float* Xb = X + (size_t)bz * Cin * Tin;
    int m0 = blockIdx.y << 6, col0 = blockIdx.x << 6;
    int tx = tid & 15, ty = tid >> 4;
    float acc[4][4] = {};
    int sm = tid & 63, sks = (tid >> 6) << 2;
    int bkk = tid >> 4, btof = (tid & 15) << 2;
    for (int k0 = 0; k0 < K; k0 += 16) {
        float4 av = *(const float4*)&Wc[(size_t)(m0 + sm) * K + k0 + sks];
        As[sks + 0][sm] = av.x; As[sks + 1][sm] = av.y;
        As[sks + 2][sm] = av.z; As[sks + 3][sm] = av.w;
        {
            int kg = k0 + bkk, i = kg >> 1, par = kg & 1;
            const float* xr = Xb + (size_t)i * Tin;
            #pragma unroll
            for (int j = 0; j < 4; ++j) {
                int t = col0 + btof + j + par;
                if (t > Tin - 1) t = Tin - 1;
                Bs[bkk][btof + j] = xr[t];
            }
        }
        __syncthreads();
        #pragma unroll
        for (int kk = 0; kk < 16; ++kk) {
            float4 a4 = *(const float4*)&As[kk][ty << 2];
            float4 b4 = *(const float4*)&Bs[kk][tx << 2];
            float a[4] = {a4.x, a4.y, a4.z, a4.w};
            float bb[4] = {b4.x, b4.y, b4.z, b4.w};
            #pragma unroll
            for (int i = 0; i < 4; ++i)
                #pragma unroll
                for (int j = 0; j < 4; ++j)
                    acc[i][j] = fmaf(a[i], bb[j], acc[i][j]);
        }
        __syncthreads();
    }
    #pragma unroll
    for (int i = 0; i < 4; ++i) {
        int m = m0 + (ty << 2) + i;
        float bv = bias[m];
        #pragma unroll
        for (int j = 0; j < 4; ++j) {
            int col = col0 + (tx << 2) + j;
            if (col < Tout)
                Y[((size_t)bz * Cout + m) * Tout + col] = fmaxf(acc[i][j] + bv, 0.f);
        }
    }
}

__global__ __launch_bounds__(256) void adjbce_kernel(const float* __restrict__ c2,
                                                     const float* __restrict__ Wfcj,
                                                     const float* __restrict__ bfcj,
                                                     const float* __restrict__ adj,
                                                     const int* __restrict__ nmask,
                                                     float* __restrict__ out_adj,
                                                     double* __restrict__ acc_bce,
                                                     int b0) {
    __shared__ float cs[8][126];
    __shared__ int smn[8];
    __shared__ float sred[4];
    int tid = threadIdx.x;
    int lbase = blockIdx.x * 8;
    size_t growbase = (size_t)b0 * Nn + lbase;
    int gb = (int)(growbase >> 9);
    for (int e = tid; e < 8 * 126; e += 256) {
        int r = e / 126, k = e - r * 126;
        cs[r][k] = c2[(size_t)(lbase + r) * 126 + k];
    }
    if (tid < 8) smn[tid] = nmask[growbase + tid];
    __syncthreads();
    int j0 = tid, j1 = tid + 256;
    float l0[8], l1[8];
    float bj0 = bfcj[j0], bj1 = bfcj[j1];
    #pragma unroll
    for (int r = 0; r < 8; ++r) { l0[r] = bj0; l1[r] = bj1; }
    for (int k = 0; k < 126; ++k) {
        float w0 = Wfcj[k * Nn + j0];
        float w1 = Wfcj[k * Nn + j1];
        #pragma unroll
        for (int r = 0; r < 8; ++r) {
            float cv = cs[r][k];
            l0[r] = fmaf(cv, w0, l0[r]);
            l1[r] = fmaf(cv, w1, l1[r]);
        }
    }
    int cm0 = nmask[(size_t)(gb << 9) + j0];
    int cm1 = nmask[(size_t)(gb << 9) + j1];
    float bsum = 0.f;
    #pragma unroll
    for (int r = 0; r < 8; ++r) {
        size_t grow = growbase + r;
        int n = (int)(grow & 511);
        int mn = smn[r];
        float a0 = adj[grow * Nn + j0];
        float a1 = adj[grow * Nn + j1];
        out_adj[grow * Nn + j0] = l0[r];
        out_adj[grow * Nn + j1] = l1[r];
        bool ab0 = (mn != 0) && (cm0 != 0) && ((j0 == n) || (a0 > 0.f));
        bool ab1 = (mn != 0) && (cm1 != 0) && ((j1 == n) || (a1 > 0.f));
        bsum += fmaxf(l0[r], 0.f) - (ab0 ? l0[r] : 0.f) + log1pf(expf(-fabsf(l0[r])));
        bsum += fmaxf(l1[r], 0.f) - (ab1 ? l1[r] : 0.f) + log1pf(expf(-fabsf(l1[r])));
    }
    #pragma unroll
    for (int o = 32; o > 0; o >>= 1) bsum += __shfl_xor(bsum, o);
    if ((tid & 63) == 0) sred[tid >> 6] = bsum;
    __syncthreads();
    if (tid == 0) atomicAdd(acc_bce, (double)(sred[0] + sred[1] + sred[2] + sred[3]));
}

// ================= final loss =================
__global__ void loss_kernel(const double* __restrict__ acc, float* __restrict__ out) {
    double ce  = acc[0] / 32768.0;
    double bce = acc[1] / 16777216.0;
    double mse = acc[2] / 163840.0;
    double kl  = -0.5 * acc[3];
    double bm = (mse != 0.0) ? fabs(ce + bce) : 0.0;   // beta*mse
    out[0] = (float)(ce + bm + bce + 1e-3 * kl);
}

extern "C" void kernel_launch(void* const* d_in, const int* in_sizes, int n_in,
                              void* d_out, int out_size, void* d_ws, size_t ws_size,
                              hipStream_t stream) {
    const float* x      = (const float*)d_in[0];
    const float* adj    = (const float*)d_in[1];
    const int*   nmask  = (const int*)d_in[2];
    const float* eps    = (const float*)d_in[3];
    const float* W_rel  = (const float*)d_in[4];
    const float* b_rel  = (const float*)d_in[5];
    const float* W_root = (const float*)d_in[6];
    const float* W_mu   = (const float*)d_in[7];
    const float* b_mu   = (const float*)d_in[8];
    const float* W_lv   = (const float*)d_in[9];
    const float* b_lv   = (const float*)d_in[10];
    const float* Wx1    = (const float*)d_in[11];
    const float* bx1    = (const float*)d_in[12];
    const float* Wx2    = (const float*)d_in[13];
    const float* bx2    = (const float*)d_in[14];
    const float* Wx3    = (const float*)d_in[15];
    const float* bx3    = (const float*)d_in[16];
    const float* Wa1    = (const float*)d_in[17];
    const float* ba1    = (const float*)d_in[18];
    const float* Wa2    = (const float*)d_in[19];
    const float* ba2    = (const float*)d_in[20];
    const float* Wa3    = (const float*)d_in[21];
    const float* ba3    = (const float*)d_in[22];
    const float* Wc1    = (const float*)d_in[23];
    const float* bc1    = (const float*)d_in[24];
    const float* Wc2    = (const float*)d_in[25];
    const float* bc2    = (const float*)d_in[26];
    const float* W_fcx  = (const float*)d_in[27];
    const float* b_fcx  = (const float*)d_in[28];
    const float* W_fca  = (const float*)d_in[29];
    const float* b_fca  = (const float*)d_in[30];
    const float* W_fcj  = (const float*)d_in[31];
    const float* b_fcj  = (const float*)d_in[32];

    float* out = (float*)d_out;
    char* region = (char*)(out + OUT_ADJ);
    ushort* t1 = (ushort*)(region + T1_OFF);
    ushort* t2 = (ushort*)(region + T2_OFF);
    ushort* hx = (ushort*)(region + HX_OFF);
    float*  Zf = (float*)(region + Z_OFF);
    ushort* Zb = (ushort*)(region + Z_OFF);
    float*  axs_g = (float*)(region + AXS_OFF);

    // MLP-phase weights in region (dead before conv phase)
    ushort* wt_x1  = (ushort*)(region + WT_OFF);
    ushort* wt_x2  = wt_x1 + 65536;
    ushort* wt_x3  = wt_x2 + 262144;
    ushort* wt_a1  = wt_x3 + 131072;
    ushort* wt_a2  = wt_a1 + 65536;
    ushort* wt_a3  = wt_a2 + 262144;
    ushort* wt_mu  = wt_a3 + 131072;
    ushort* wt_lv  = wt_mu + 32768;
    ushort* wt_fcx = wt_lv + 32768;
    ushort* wt_enc = wt_fcx + 36864;       // [256][64] bf16 hi|lo combined W_rel/W_root

    // conv-phase weights + buffers in d_ws
    double* acc = (double*)d_ws;
    ushort* wc1b   = (ushort*)((char*)d_ws + 256);
    ushort* wc2b   = wc1b + 262144;
    ushort* wt_fcj = wc2b + 262144;
    // abits (2 MB) lives in d_ws so the out_adj write can't clobber it (race-safe).
    ushort* abits_ws = (ushort*)((char*)d_ws + 1179904);
    char* convbuf = (char*)d_ws + 1179904 + 2097152;
    bool fastConv = ws_size >= (size_t)1179904 + 2097152 + 196608;
    // fallback: abits unread -> park it in the region gap (clobbered later, harmless)
    ushort* abits = fastConv ? abits_ws : (ushort*)(region + ABITS_FB_OFF);

    hipMemsetAsync(d_ws, 0, 256, stream);

    // ---- prep table ----
    PTable tab;
    int t0 = 0;
    auto setT = [&](int i, const float* s, ushort* d, int R, int C, int Cp, int Kp) {
        tab.d[i] = {s, d, R, C, Cp, Kp, t0, 0};
        t0 += ((Cp + 31) / 32) * ((Kp + 31) / 32);
    };
    setT(0, Wx1, wt_x1, 128, 512, 512, 128);
    setT(1, Wx2, wt_x2, 512, 512, 512, 512);
    setT(2, Wx3, wt_x3, 512, 256, 256, 512);
    setT(3, Wa1, wt_a1, 128, 512, 512, 128);
    setT(4, Wa2, wt_a2, 512, 512, 512, 512);
    setT(5, Wa3, wt_a3, 512, 256, 256, 512);
    setT(6, W_mu, wt_mu, 256, 128, 128, 256);
    setT(7, W_lv, wt_lv, 256, 128, 128, 256);
    // encoder combined weight [256][64] hi|lo (disjoint strided writes, koff = mode-64)
    setT(8,  W_rel,  wt_enc, 10, 256, 256, 10); tab.d[8].mode  = 64 + 0;    // rel hi  k 0..9
    setT(9,  W_root, wt_enc, 10, 256, 256, 10); tab.d[9].mode  = 64 + 10;   // root hi k 10..19
    setT(10, W_rel,  wt_enc, 0,  0,   256, 12); tab.d[10].mode = 64 + 20;   // zeros   k 20..31
    setT(11, W_rel,  wt_enc, 10, 256, 256, 10); tab.d[11].mode = 64 + 32;   // rel lo  k 32..41
    setT(12, W_root, wt_enc, 10, 256, 256, 10); tab.d[12].mode = 64 + 42;   // root lo k 42..51
    setT(13, W_rel,  wt_enc, 0,  0,   256, 12); tab.d[13].mode = 64 + 52;   // zeros   k 52..63
    setT(14, W_fcx, wt_fcx, 256, 140, 144, 256);
    int t_nofcj = t0;
    setT(15, W_fcj, wt_fcj, 126, 512, 512, 128);
    tab.d[16] = {Wc1, wc1b, 262144, 0, 0, 0, t0, 1}; t0 += 32;
    tab.d[17] = {Wc2, wc2b, 262144, 0, 0, 0, t0, 1}; t0 += 32;
    prep_kernel<<<fastConv ? t0 : t_nofcj, 256, 0, stream>>>(tab);

    // ---- encoder: memory-heavy agg (+ adj>0 bitpack) + all-MFMA enc2 ----
    agg_kernel<<<ROWS / 16, 256, 0, stream>>>(adj, x, axs_g, abits);
    enc2_kernel<<<ROWS / 16, 256, 0, stream>>>(axs_g, wt_enc, b_rel, nmask,
                                               wt_mu, b_mu, wt_lv, b_lv, eps,
                                               fastConv ? (void*)Zb : (void*)Zf,
                                               fastConv ? 1 : 0, acc + 3);

    // ---- MLP chains (fastConv: Z is bf16 -> a_bf16 staging, no conversion) ----
    int zb = fastConv ? 1 : 0;
    for (int c = 0; c < 2; ++c) {
        int r0 = c * CH;
        const void* Zc = fastConv ? (const void*)(Zb + (size_t)r0 * Ll)
                                  : (const void*)(Zf + (size_t)r0 * Ll);
        mgemm_kernel<<<dim3(4, 128), 256, 0, stream>>>(Zc, zb, wt_x1, bx1, t1, 0, 512, 128, 512, 1);
        mgemm_kernel<<<dim3(4, 128), 256, 0, stream>>>(t1, 1, wt_x2, bx2, t2, 0, 512, 512, 512, 1);
        mgemm_kernel<<<dim3(2, 128), 256, 0, stream>>>(t2, 1, wt_x3, bx3, hx, 0, 256, 512, 256, 0);
        ce_kernel<<<CH / 16, 256, 0, stream>>>(hx, wt_fcx, b_fcx, x, out + OUT_CLASS, acc + 0, r0);
    }
    for (int c = 0; c < 2; ++c) {
        int r0 = c * CH;
        const void* Zc = fastConv ? (const void*)(Zb + (size_t)r0 * Ll)
                                  : (const void*)(Zf + (size_t)r0 * Ll);
        mgemm_kernel<<<dim3(4, 128), 256, 0, stream>>>(Zc, zb, wt_a1, ba1, t1, 0, 512, 128, 512, 1);
        mgemm_kernel<<<dim3(4, 128), 256, 0, stream>>>(t1, 1, wt_a2, ba2, t2, 0, 512, 512, 512, 1);
        mgemm_kernel<<<dim3(2, 128), 256, 0, stream>>>(t2, 1, wt_a3, ba3, hx, 0, 256, 512, 256, 0);
        atom_kernel<<<CH / 64, 256, 0, stream>>>(hx, W_fca, b_fca, x, out + OUT_ATOM, acc + 2, r0);
    }

    // ---- conv path + adj head + dedicated BCE pass (abits-based) ----
    if (fastConv) {
        size_t avail = ws_size - 1179904 - 2097152;
        int NB = 64;
        while (NB > 1 && (size_t)NB * 196608 > avail) NB >>= 1;
        ushort* c1 = (ushort*)convbuf;
        ushort* c2 = c1 + (size_t)NB * 32768;
        for (int b0 = 0; b0 < 64; b0 += NB) {
            convmfma_kernel<<<dim3(1, 2, NB), 256, 0, stream>>>(Zb + (size_t)b0 * 65536, 1, 65536,
                                                               wc1b, bc1, c1, 256, 1024, 127);
            convmfma_kernel<<<dim3(1, 4, NB), 256, 0, stream>>>(c1, 1, 32768,
                                                               wc2b, bc2, c2, 512, 512, 126);
            mgemm_kernel<<<dim3(4, NB * 4), 256, 0, stream>>>(c2, 1, wt_fcj, b_fcj,
                                                              out + OUT_ADJ + (size_t)b0 * 262144, 1,
                                                              512, 128, 512, 0);
        }
        bce2_kernel<<<1024, 256, 0, stream>>>(out + OUT_ADJ, abits, nmask, acc + 1);
    } else {
        size_t avail = (ws_size > 256) ? ws_size - 256 : 0;
        int NB = 64;
        while (NB > 1 && (size_t)NB * 388096 > avail) NB >>= 1;
        float* c1 = (float*)((char*)d_ws + 256);
        float* c2 = (float*)((char*)d_ws + 256 + (size_t)NB * 256 * 127 * 4);
        for (int b0 = 0; b0 < 64; b0 += NB) {
            convgemm_kernel<<<dim3(2, 4, NB), 256, 0, stream>>>(Zf + (size_t)b0 * 65536, Wc1, bc1, c1, 512, 128, 256);
            convgemm_kernel<<<dim3(2, 8, NB), 256, 0, stream>>>(c1, Wc2, bc2, c2, 256, 127, 512);
            adjbce_kernel<<<NB * Nn / 8, 256, 0, stream>>>(c2, W_fcj, b_fcj, adj, nmask,
                                                           out + OUT_ADJ, acc + 1, b0);
        }
    }

    loss_kernel<<<1, 1, 0, stream>>>(acc, out);
}